// Round 1
// baseline (547.012 us; speedup 1.0000x reference)
//
#include <hip/hip_runtime.h>
#include <hip/hip_bf16.h>

typedef __bf16 bf16x8 __attribute__((ext_vector_type(8)));
typedef float  f32x4  __attribute__((ext_vector_type(4)));
typedef __hip_bfloat16 bf16_t;

constexpr int CB  = 2;
constexpr int CNQ = 512;
constexpr int CNC = 2048;
constexpr int CD  = 768;
constexpr int CH  = 8;
constexpr int CHD = 96;
constexpr int CFFN = 3072;

static __device__ __forceinline__ float gelu_f(float x) {
    return 0.5f * x * (1.0f + erff(x * 0.70710678118654752f));
}

// ---------------- LayerNorm: f32 in -> bf16 out, one block per row (D=768) ----------------
__global__ __launch_bounds__(256) void ln_kernel(const float* __restrict__ x,
                                                 const float* __restrict__ g,
                                                 const float* __restrict__ b,
                                                 bf16_t* __restrict__ out) {
    __shared__ float red[8];
    long row = blockIdx.x;
    const float* xr = x + row * CD;
    int t = threadIdx.x;
    float v0 = xr[t], v1 = xr[t + 256], v2 = xr[t + 512];
    float s  = v0 + v1 + v2;
    float sq = v0 * v0 + v1 * v1 + v2 * v2;
    #pragma unroll
    for (int o = 32; o; o >>= 1) { s += __shfl_xor(s, o); sq += __shfl_xor(sq, o); }
    if ((t & 63) == 0) { red[t >> 6] = s; red[4 + (t >> 6)] = sq; }
    __syncthreads();
    s  = red[0] + red[1] + red[2] + red[3];
    sq = red[4] + red[5] + red[6] + red[7];
    float mean = s * (1.0f / 768.0f);
    float var  = sq * (1.0f / 768.0f) - mean * mean;
    float inv  = rsqrtf(var + 1e-5f);
    bf16_t* orow = out + row * CD;
    orow[t]       = __float2bfloat16((v0 - mean) * inv * g[t]       + b[t]);
    orow[t + 256] = __float2bfloat16((v1 - mean) * inv * g[t + 256] + b[t + 256]);
    orow[t + 512] = __float2bfloat16((v2 - mean) * inv * g[t + 512] + b[t + 512]);
}

// ---------------- f32 -> bf16 convert (n % 1024 == 0) ----------------
__global__ __launch_bounds__(256) void cvt_kernel(const float* __restrict__ in,
                                                  bf16_t* __restrict__ out, long n) {
    long i = ((long)blockIdx.x * 256 + threadIdx.x) * 4;
    float4 v = *(const float4*)&in[i];
    out[i]     = __float2bfloat16(v.x);
    out[i + 1] = __float2bfloat16(v.y);
    out[i + 2] = __float2bfloat16(v.z);
    out[i + 3] = __float2bfloat16(v.w);
}

// ---------------- weight transpose + convert: W (K x N) f32 -> Wt (N x K) bf16 ----------------
__global__ __launch_bounds__(256) void wtrans_kernel(const float* __restrict__ W,
                                                     bf16_t* __restrict__ Wt, int K, int N) {
    __shared__ float tile[32][33];
    int tx = threadIdx.x & 31, ty = threadIdx.x >> 5;
    int bx = blockIdx.x, by = blockIdx.y;
    #pragma unroll
    for (int i = 0; i < 4; ++i) {
        int k = by * 32 + ty + i * 8;
        tile[ty + i * 8][tx] = W[(long)k * N + bx * 32 + tx];
    }
    __syncthreads();
    #pragma unroll
    for (int i = 0; i < 4; ++i) {
        int n = bx * 32 + ty + i * 8;
        Wt[(long)n * K + by * 32 + tx] = __float2bfloat16(tile[tx][ty + i * 8]);
    }
}

// ---------------- relative coordinate bias: gelu(delta@w1+b1)@w2+b2 -> (B,H,NQ,NC) bf16 ----------------
__global__ __launch_bounds__(256) void relbias_kernel(const float* __restrict__ qc,
                                                      const float* __restrict__ cc,
                                                      const float* __restrict__ w1,
                                                      const float* __restrict__ b1,
                                                      const float* __restrict__ w2,
                                                      const float* __restrict__ b2,
                                                      bf16_t* __restrict__ bias) {
    long idx = (long)blockIdx.x * 256 + threadIdx.x;   // over B*NQ*NC
    int  kk = (int)(idx & (CNC - 1));
    long t2 = idx >> 11;
    int  q  = (int)(t2 & (CNQ - 1));
    int  b  = (int)(t2 >> 9);
    float d0 = qc[((long)b * CNQ + q) * 2]     - cc[((long)b * CNC + kk) * 2];
    float d1 = qc[((long)b * CNQ + q) * 2 + 1] - cc[((long)b * CNC + kk) * 2 + 1];
    float acc[CH] = {};
    #pragma unroll 8
    for (int j = 0; j < 64; ++j) {
        float h = fmaf(d0, w1[j], fmaf(d1, w1[64 + j], b1[j]));
        h = gelu_f(h);
        #pragma unroll
        for (int hh = 0; hh < CH; ++hh) acc[hh] = fmaf(h, w2[j * CH + hh], acc[hh]);
    }
    long qk = (long)q * CNC + kk;
    #pragma unroll
    for (int hh = 0; hh < CH; ++hh)
        bias[(long)(b * CH + hh) * CNQ * CNC + qk] = __float2bfloat16(acc[hh] + b2[hh]);
}

// ---------------- row softmax in place: f32 row -> bf16 row (written over row start) ----------------
template<int NPT>
__global__ __launch_bounds__(256) void softmax_kernel(float* __restrict__ S, long ld) {
    __shared__ float red[8];
    long row = blockIdx.x;
    float* base = S + row * ld;
    int t = threadIdx.x;
    const int c0 = t * NPT;
    float v[NPT];
    #pragma unroll
    for (int i = 0; i < NPT; ++i) v[i] = base[c0 + i];
    float m = v[0];
    #pragma unroll
    for (int i = 1; i < NPT; ++i) m = fmaxf(m, v[i]);
    #pragma unroll
    for (int o = 32; o; o >>= 1) m = fmaxf(m, __shfl_xor(m, o));
    if ((t & 63) == 0) red[t >> 6] = m;
    __syncthreads();                      // also guarantees all loads done before bf16 writes
    m = fmaxf(fmaxf(red[0], red[1]), fmaxf(red[2], red[3]));
    float s = 0.0f;
    #pragma unroll
    for (int i = 0; i < NPT; ++i) { v[i] = __expf(v[i] - m); s += v[i]; }
    #pragma unroll
    for (int o = 32; o; o >>= 1) s += __shfl_xor(s, o);
    __syncthreads();
    if ((t & 63) == 0) red[4 + (t >> 6)] = s;
    __syncthreads();
    s = red[4] + red[5] + red[6] + red[7];
    float inv = 1.0f / s;
    bf16_t* ob = (bf16_t*)base;
    #pragma unroll
    for (int i = 0; i < NPT; ++i) ob[c0 + i] = __float2bfloat16(v[i] * inv);
}

// ---------------- generic NT MFMA GEMM: C[z] = scale*(A[z] @ Bt[z]^T) + epilogue ----------------
// A: M x K row-major bf16 (ldA elems). Bt: N x K row-major bf16 (row n = column n of B).
// OUT: 0 f32 plain, 1 bf16 plain, 2 bf16 head-split (B,H,NR,HD), 3 bf16 head-split-T (B,H,HD,NR),
//      4 bf16 merge96: z=(b,h), write (b, row, h*HD+col) into (B,NQ,D).
template<int MF, int NF, int BK, int OUT, bool BIAS, bool B2D, bool GELU_E, bool RES>
__global__ __launch_bounds__(256) void gemm_nt(
        const bf16_t* __restrict__ A, long ldA, long zsA,
        const bf16_t* __restrict__ Bt, long ldB, long zsB,
        const float* __restrict__ bias,
        const bf16_t* __restrict__ b2d, long zs2d, long ld2d,
        const float* __restrict__ res,
        void* __restrict__ Cout, long ldC, long zsC,
        int K, int NR, float scale) {
    constexpr int BM = MF * 32, BN = NF * 32;
    constexpr int PAD = 24, LDT = BK + PAD;
    constexpr int SEGS = BK / 8;
    static_assert((BM * SEGS) % 256 == 0 && (BN * SEGS) % 256 == 0, "staging divisibility");
    __shared__ __bf16 As[BM * LDT];
    __shared__ __bf16 Bs[BN * LDT];
    const int tid = threadIdx.x;
    const int z = blockIdx.z;
    const int m0 = blockIdx.y * BM, n0 = blockIdx.x * BN;
    const bf16_t* Ab = A + (long)z * zsA + (long)m0 * ldA;
    const bf16_t* Bb = Bt + (long)z * zsB + (long)n0 * ldB;
    const int w = tid >> 6, lane = tid & 63;
    const int wm = w >> 1, wn = w & 1;
    const int l15 = lane & 15, l4 = lane >> 4;
    f32x4 acc[MF][NF] = {};
    for (int k0 = 0; k0 < K; k0 += BK) {
        #pragma unroll
        for (int it = 0; it < (BM * SEGS) / 256; ++it) {
            int c = tid + it * 256;
            int r = c / SEGS, sg = c % SEGS;
            *(bf16x8*)&As[r * LDT + sg * 8] = *(const bf16x8*)&Ab[(long)r * ldA + k0 + sg * 8];
        }
        #pragma unroll
        for (int it = 0; it < (BN * SEGS) / 256; ++it) {
            int c = tid + it * 256;
            int r = c / SEGS, sg = c % SEGS;
            *(bf16x8*)&Bs[r * LDT + sg * 8] = *(const bf16x8*)&Bb[(long)r * ldB + k0 + sg * 8];
        }
        __syncthreads();
        #pragma unroll
        for (int s = 0; s < BK / 32; ++s) {
            bf16x8 af[MF], bfr[NF];
            #pragma unroll
            for (int i = 0; i < MF; ++i)
                af[i] = *(const bf16x8*)&As[(wm * MF * 16 + i * 16 + l15) * LDT + s * 32 + l4 * 8];
            #pragma unroll
            for (int j = 0; j < NF; ++j)
                bfr[j] = *(const bf16x8*)&Bs[(wn * NF * 16 + j * 16 + l15) * LDT + s * 32 + l4 * 8];
            #pragma unroll
            for (int i = 0; i < MF; ++i)
                #pragma unroll
                for (int j = 0; j < NF; ++j)
                    acc[i][j] = __builtin_amdgcn_mfma_f32_16x16x32_bf16(af[i], bfr[j], acc[i][j], 0, 0, 0);
        }
        __syncthreads();
    }
    #pragma unroll
    for (int i = 0; i < MF; ++i) {
        const int rbase = m0 + wm * MF * 16 + i * 16 + l4 * 4;
        #pragma unroll
        for (int j = 0; j < NF; ++j) {
            const int col = n0 + wn * NF * 16 + j * 16 + l15;
            #pragma unroll
            for (int r = 0; r < 4; ++r) {
                int row = rbase + r;
                float v = acc[i][j][r] * scale;
                if constexpr (BIAS) v += bias[col];
                if constexpr (B2D)  v += __bfloat162float(b2d[(long)z * zs2d + (long)row * ld2d + col]);
                if constexpr (GELU_E) v = gelu_f(v);
                if constexpr (RES)  v += res[(long)row * ldC + col];
                if constexpr (OUT == 0) {
                    ((float*)Cout)[(long)z * zsC + (long)row * ldC + col] = v;
                } else if constexpr (OUT == 1) {
                    ((bf16_t*)Cout)[(long)z * zsC + (long)row * ldC + col] = __float2bfloat16(v);
                } else if constexpr (OUT == 2) {
                    int bb = row / NR, n = row - bb * NR;
                    int hh = col / CHD, dd = col - hh * CHD;
                    ((bf16_t*)Cout)[((long)(bb * CH + hh) * NR + n) * CHD + dd] = __float2bfloat16(v);
                } else if constexpr (OUT == 3) {
                    int bb = row / NR, n = row - bb * NR;
                    int hh = col / CHD, dd = col - hh * CHD;
                    ((bf16_t*)Cout)[((long)(bb * CH + hh) * CHD + dd) * NR + n] = __float2bfloat16(v);
                } else { // OUT == 4
                    int bb = z / CH, hh = z - bb * CH;
                    ((bf16_t*)Cout)[((long)bb * CNQ + row) * CD + hh * CHD + col] = __float2bfloat16(v);
                }
            }
        }
    }
}

extern "C" void kernel_launch(void* const* d_in, const int* in_sizes, int n_in,
                              void* d_out, int out_size, void* d_ws, size_t ws_size,
                              hipStream_t stream) {
    const float* query_state    = (const float*)d_in[0];
    const float* context_k      = (const float*)d_in[1];
    const float* context_v      = (const float*)d_in[2];
    const float* query_coords   = (const float*)d_in[3];
    const float* context_coords = (const float*)d_in[4];
    const float* sn_g = (const float*)d_in[5];  const float* sn_b = (const float*)d_in[6];
    const float* sa_wq = (const float*)d_in[7];  const float* sa_bq = (const float*)d_in[8];
    const float* sa_wk = (const float*)d_in[9];  const float* sa_bk = (const float*)d_in[10];
    const float* sa_wv = (const float*)d_in[11]; const float* sa_bv = (const float*)d_in[12];
    const float* sa_wo = (const float*)d_in[13]; const float* sa_bo = (const float*)d_in[14];
    const float* cn_g = (const float*)d_in[15];  const float* cn_b = (const float*)d_in[16];
    const float* ca_wq = (const float*)d_in[17]; const float* ca_bq = (const float*)d_in[18];
    const float* ca_wk = (const float*)d_in[19]; const float* ca_bk = (const float*)d_in[20];
    const float* ca_wv = (const float*)d_in[21]; const float* ca_bv = (const float*)d_in[22];
    const float* ca_wo = (const float*)d_in[23]; const float* ca_bo = (const float*)d_in[24];
    const float* rb_w1 = (const float*)d_in[25]; const float* rb_b1 = (const float*)d_in[26];
    const float* rb_w2 = (const float*)d_in[27]; const float* rb_b2 = (const float*)d_in[28];
    const float* fn_g = (const float*)d_in[29];  const float* fn_b = (const float*)d_in[30];
    const float* ffn_w1 = (const float*)d_in[31]; const float* ffn_b1 = (const float*)d_in[32];
    const float* ffn_w2 = (const float*)d_in[33]; const float* ffn_b2 = (const float*)d_in[34];
    float* out = (float*)d_out;

    char* p = (char*)d_ws;
    auto alloc = [&](size_t bytes) -> char* {
        char* r = p; p += (bytes + 255) & ~(size_t)255; return r;
    };
    const size_t WDD = (size_t)CD * CD, WDF = (size_t)CD * CFFN;
    bf16_t* sa_wq_t = (bf16_t*)alloc(WDD * 2);
    bf16_t* sa_wk_t = (bf16_t*)alloc(WDD * 2);
    bf16_t* sa_wv_t = (bf16_t*)alloc(WDD * 2);
    bf16_t* sa_wo_t = (bf16_t*)alloc(WDD * 2);
    bf16_t* ca_wq_t = (bf16_t*)alloc(WDD * 2);
    bf16_t* ca_wk_t = (bf16_t*)alloc(WDD * 2);
    bf16_t* ca_wv_t = (bf16_t*)alloc(WDD * 2);
    bf16_t* ca_wo_t = (bf16_t*)alloc(WDD * 2);
    bf16_t* ffn_w1_t = (bf16_t*)alloc(WDF * 2);
    bf16_t* ffn_w2_t = (bf16_t*)alloc(WDF * 2);
    bf16_t* ln_buf   = (bf16_t*)alloc((size_t)CB * CNQ * CD * 2);
    bf16_t* q_split  = (bf16_t*)alloc((size_t)CB * CH * CNQ * CHD * 2);
    bf16_t* k_split  = (bf16_t*)alloc((size_t)CB * CH * CNQ * CHD * 2);
    bf16_t* v_splitT = (bf16_t*)alloc((size_t)CB * CH * CNQ * CHD * 2);
    bf16_t* ck_b     = (bf16_t*)alloc((size_t)CB * CNC * CD * 2);
    bf16_t* cv_b     = (bf16_t*)alloc((size_t)CB * CNC * CD * 2);
    bf16_t* kc_split = (bf16_t*)alloc((size_t)CB * CH * CNC * CHD * 2);
    bf16_t* vc_splitT= (bf16_t*)alloc((size_t)CB * CH * CNC * CHD * 2);
    float*  S        = (float*)alloc((size_t)CB * CH * CNQ * CNC * 4);
    bf16_t* bias2d   = (bf16_t*)alloc((size_t)CB * CH * CNQ * CNC * 2);
    bf16_t* attn_m   = (bf16_t*)alloc((size_t)CB * CNQ * CD * 2);
    float*  xbuf     = (float*)alloc((size_t)CB * CNQ * CD * 4);
    bf16_t* ffn_h    = (bf16_t*)alloc((size_t)CB * CNQ * CFFN * 2);

    const dim3 tb(256);
    const float qk_scale = 0.10206207261596575f;  // 96^-0.5

    // weights -> bf16 transposed
    wtrans_kernel<<<dim3(CD / 32, CD / 32), tb, 0, stream>>>(sa_wq, sa_wq_t, CD, CD);
    wtrans_kernel<<<dim3(CD / 32, CD / 32), tb, 0, stream>>>(sa_wk, sa_wk_t, CD, CD);
    wtrans_kernel<<<dim3(CD / 32, CD / 32), tb, 0, stream>>>(sa_wv, sa_wv_t, CD, CD);
    wtrans_kernel<<<dim3(CD / 32, CD / 32), tb, 0, stream>>>(sa_wo, sa_wo_t, CD, CD);
    wtrans_kernel<<<dim3(CD / 32, CD / 32), tb, 0, stream>>>(ca_wq, ca_wq_t, CD, CD);
    wtrans_kernel<<<dim3(CD / 32, CD / 32), tb, 0, stream>>>(ca_wk, ca_wk_t, CD, CD);
    wtrans_kernel<<<dim3(CD / 32, CD / 32), tb, 0, stream>>>(ca_wv, ca_wv_t, CD, CD);
    wtrans_kernel<<<dim3(CD / 32, CD / 32), tb, 0, stream>>>(ca_wo, ca_wo_t, CD, CD);
    wtrans_kernel<<<dim3(CFFN / 32, CD / 32), tb, 0, stream>>>(ffn_w1, ffn_w1_t, CD, CFFN);
    wtrans_kernel<<<dim3(CD / 32, CFFN / 32), tb, 0, stream>>>(ffn_w2, ffn_w2_t, CFFN, CD);
    // context k/v -> bf16
    cvt_kernel<<<(CB * CNC * CD) / 1024, tb, 0, stream>>>(context_k, ck_b, (long)CB * CNC * CD);
    cvt_kernel<<<(CB * CNC * CD) / 1024, tb, 0, stream>>>(context_v, cv_b, (long)CB * CNC * CD);
    // relative coordinate bias
    relbias_kernel<<<(CB * CNQ * CNC) / 256, tb, 0, stream>>>(query_coords, context_coords,
                                                              rb_w1, rb_b1, rb_w2, rb_b2, bias2d);
    // ---- self attention ----
    ln_kernel<<<CB * CNQ, tb, 0, stream>>>(query_state, sn_g, sn_b, ln_buf);
    gemm_nt<4,2,64,2,true,false,false,false><<<dim3(CD / 64, (CB * CNQ) / 128, 1), tb, 0, stream>>>(
        ln_buf, CD, 0, sa_wq_t, CD, 0, sa_bq, nullptr, 0, 0, nullptr, q_split, 0, 0, CD, CNQ, 1.0f);
    gemm_nt<4,2,64,2,true,false,false,false><<<dim3(CD / 64, (CB * CNQ) / 128, 1), tb, 0, stream>>>(
        ln_buf, CD, 0, sa_wk_t, CD, 0, sa_bk, nullptr, 0, 0, nullptr, k_split, 0, 0, CD, CNQ, 1.0f);
    gemm_nt<4,2,64,3,true,false,false,false><<<dim3(CD / 64, (CB * CNQ) / 128, 1), tb, 0, stream>>>(
        ln_buf, CD, 0, sa_wv_t, CD, 0, sa_bv, nullptr, 0, 0, nullptr, v_splitT, 0, 0, CD, CNQ, 1.0f);
    gemm_nt<4,2,96,0,false,false,false,false><<<dim3(CNQ / 64, CNQ / 128, CB * CH), tb, 0, stream>>>(
        q_split, CHD, (long)CNQ * CHD, k_split, CHD, (long)CNQ * CHD,
        nullptr, nullptr, 0, 0, nullptr, S, CNQ, (long)CNQ * CNQ, CHD, 0, qk_scale);
    softmax_kernel<2><<<CB * CH * CNQ, tb, 0, stream>>>(S, CNQ);
    gemm_nt<4,3,64,4,false,false,false,false><<<dim3(1, CNQ / 128, CB * CH), tb, 0, stream>>>(
        (const bf16_t*)S, 2 * CNQ, (long)CNQ * 2 * CNQ, v_splitT, CNQ, (long)CHD * CNQ,
        nullptr, nullptr, 0, 0, nullptr, attn_m, 0, 0, CNQ, CNQ, 1.0f);
    gemm_nt<4,2,64,0,true,false,false,true><<<dim3(CD / 64, (CB * CNQ) / 128, 1), tb, 0, stream>>>(
        attn_m, CD, 0, sa_wo_t, CD, 0, sa_bo, nullptr, 0, 0, query_state, xbuf, CD, 0, CD, 0, 1.0f);
    // ---- cross attention ----
    ln_kernel<<<CB * CNQ, tb, 0, stream>>>(xbuf, cn_g, cn_b, ln_buf);
    gemm_nt<4,2,64,2,true,false,false,false><<<dim3(CD / 64, (CB * CNQ) / 128, 1), tb, 0, stream>>>(
        ln_buf, CD, 0, ca_wq_t, CD, 0, ca_bq, nullptr, 0, 0, nullptr, q_split, 0, 0, CD, CNQ, 1.0f);
    gemm_nt<4,2,64,2,true,false,false,false><<<dim3(CD / 64, (CB * CNC) / 128, 1), tb, 0, stream>>>(
        ck_b, CD, 0, ca_wk_t, CD, 0, ca_bk, nullptr, 0, 0, nullptr, kc_split, 0, 0, CD, CNC, 1.0f);
    gemm_nt<4,2,64,3,true,false,false,false><<<dim3(CD / 64, (CB * CNC) / 128, 1), tb, 0, stream>>>(
        cv_b, CD, 0, ca_wv_t, CD, 0, ca_bv, nullptr, 0, 0, nullptr, vc_splitT, 0, 0, CD, CNC, 1.0f);
    gemm_nt<4,2,96,0,false,true,false,false><<<dim3(CNC / 64, CNQ / 128, CB * CH), tb, 0, stream>>>(
        q_split, CHD, (long)CNQ * CHD, kc_split, CHD, (long)CNC * CHD,
        nullptr, bias2d, (long)CNQ * CNC, CNC, nullptr, S, CNC, (long)CNQ * CNC, CHD, 0, qk_scale);
    softmax_kernel<8><<<CB * CH * CNQ, tb, 0, stream>>>(S, CNC);
    gemm_nt<4,3,64,4,false,false,false,false><<<dim3(1, CNQ / 128, CB * CH), tb, 0, stream>>>(
        (const bf16_t*)S, 2 * CNC, (long)CNQ * 2 * CNC, vc_splitT, CNC, (long)CHD * CNC,
        nullptr, nullptr, 0, 0, nullptr, attn_m, 0, 0, CNC, CNQ, 1.0f);
    gemm_nt<4,2,64,0,true,false,false,true><<<dim3(CD / 64, (CB * CNQ) / 128, 1), tb, 0, stream>>>(
        attn_m, CD, 0, ca_wo_t, CD, 0, ca_bo, nullptr, 0, 0, xbuf, xbuf, CD, 0, CD, 0, 1.0f);
    // ---- FFN ----
    ln_kernel<<<CB * CNQ, tb, 0, stream>>>(xbuf, fn_g, fn_b, ln_buf);
    gemm_nt<4,2,64,1,true,false,true,false><<<dim3(CFFN / 64, (CB * CNQ) / 128, 1), tb, 0, stream>>>(
        ln_buf, CD, 0, ffn_w1_t, CD, 0, ffn_b1, nullptr, 0, 0, nullptr, ffn_h, CFFN, 0, CD, 0, 1.0f);
    gemm_nt<4,2,64,0,true,false,false,true><<<dim3(CD / 64, (CB * CNQ) / 128, 1), tb, 0, stream>>>(
        ffn_h, CFFN, 0, ffn_w2_t, CFFN, 0, ffn_b2, nullptr, 0, 0, xbuf, out, CD, 0, CFFN, 0, 1.0f);
}

// Round 5
// 516.191 us; speedup vs baseline: 1.0597x; 1.0597x over previous
//
#include <hip/hip_runtime.h>
#include <hip/hip_bf16.h>

typedef __bf16 bf16x8 __attribute__((ext_vector_type(8)));
typedef float  f32x4  __attribute__((ext_vector_type(4)));
typedef float  f32x2  __attribute__((ext_vector_type(2)));
typedef __hip_bfloat16 bf16_t;

constexpr int CB  = 2;
constexpr int CNQ = 512;
constexpr int CNC = 2048;
constexpr int CD  = 768;
constexpr int CH  = 8;
constexpr int CHD = 96;
constexpr int CFFN = 3072;

// fast gelu: x * sigmoid(1.5957692(x + 0.044715 x^3)); max abs err vs exact ~3e-4
static __device__ __forceinline__ float gelu_f(float x) {
    float x2 = x * x;
    float zn = x * fmaf(x2, -0.07135481f, -1.5957692f);   // = -1.5958(x+0.0447x^3)/x * x
    float e  = __expf(zn);
    return x * __builtin_amdgcn_rcpf(1.0f + e);
}

// ---------------- LayerNorm: f32 in -> bf16 out, one block per row (D=768) ----------------
__global__ __launch_bounds__(256) void ln_kernel(const float* __restrict__ x,
                                                 const float* __restrict__ g,
                                                 const float* __restrict__ b,
                                                 bf16_t* __restrict__ out) {
    __shared__ float red[8];
    long row = blockIdx.x;
    const float* xr = x + row * CD;
    int t = threadIdx.x;
    float v0 = xr[t], v1 = xr[t + 256], v2 = xr[t + 512];
    float s  = v0 + v1 + v2;
    float sq = v0 * v0 + v1 * v1 + v2 * v2;
    #pragma unroll
    for (int o = 32; o; o >>= 1) { s += __shfl_xor(s, o); sq += __shfl_xor(sq, o); }
    if ((t & 63) == 0) { red[t >> 6] = s; red[4 + (t >> 6)] = sq; }
    __syncthreads();
    s  = red[0] + red[1] + red[2] + red[3];
    sq = red[4] + red[5] + red[6] + red[7];
    float mean = s * (1.0f / 768.0f);
    float var  = sq * (1.0f / 768.0f) - mean * mean;
    float inv  = rsqrtf(var + 1e-5f);
    bf16_t* orow = out + row * CD;
    orow[t]       = __float2bfloat16((v0 - mean) * inv * g[t]       + b[t]);
    orow[t + 256] = __float2bfloat16((v1 - mean) * inv * g[t + 256] + b[t + 256]);
    orow[t + 512] = __float2bfloat16((v2 - mean) * inv * g[t + 512] + b[t + 512]);
}

// ---------------- f32 -> bf16 convert (n % 1024 == 0) ----------------
__global__ __launch_bounds__(256) void cvt_kernel(const float* __restrict__ in,
                                                  bf16_t* __restrict__ out, long n) {
    long i = ((long)blockIdx.x * 256 + threadIdx.x) * 4;
    float4 v = *(const float4*)&in[i];
    out[i]     = __float2bfloat16(v.x);
    out[i + 1] = __float2bfloat16(v.y);
    out[i + 2] = __float2bfloat16(v.z);
    out[i + 3] = __float2bfloat16(v.w);
}

// ---------------- weight transpose + convert: W (K x N) f32 -> Wt (N x K) bf16 ----------------
__global__ __launch_bounds__(256) void wtrans_kernel(const float* __restrict__ W,
                                                     bf16_t* __restrict__ Wt, int K, int N) {
    __shared__ float tile[32][33];
    int tx = threadIdx.x & 31, ty = threadIdx.x >> 5;
    int bx = blockIdx.x, by = blockIdx.y;
    #pragma unroll
    for (int i = 0; i < 4; ++i) {
        int k = by * 32 + ty + i * 8;
        tile[ty + i * 8][tx] = W[(long)k * N + bx * 32 + tx];
    }
    __syncthreads();
    #pragma unroll
    for (int i = 0; i < 4; ++i) {
        int n = bx * 32 + ty + i * 8;
        Wt[(long)n * K + by * 32 + tx] = __float2bfloat16(tile[tx][ty + i * 8]);
    }
}

// ---------------- relative coordinate bias: gelu(delta@w1+b1)@w2+b2 -> (B,H,NQ,NC) bf16 ----------------
__global__ __launch_bounds__(256) void relbias_kernel(const float* __restrict__ qc,
                                                      const float* __restrict__ cc,
                                                      const float* __restrict__ w1,
                                                      const float* __restrict__ b1,
                                                      const float* __restrict__ w2,
                                                      const float* __restrict__ b2,
                                                      bf16_t* __restrict__ bias) {
    long idx = (long)blockIdx.x * 256 + threadIdx.x;   // over B*NQ*NC
    int  kk = (int)(idx & (CNC - 1));
    long t2 = idx >> 11;
    int  q  = (int)(t2 & (CNQ - 1));
    int  b  = (int)(t2 >> 9);
    float d0 = qc[((long)b * CNQ + q) * 2]     - cc[((long)b * CNC + kk) * 2];
    float d1 = qc[((long)b * CNQ + q) * 2 + 1] - cc[((long)b * CNC + kk) * 2 + 1];
    f32x2 acc[4];
    #pragma unroll
    for (int i = 0; i < 4; ++i) { acc[i][0] = b2[2 * i]; acc[i][1] = b2[2 * i + 1]; }
    #pragma unroll 8
    for (int j = 0; j < 64; ++j) {
        float x = fmaf(d0, w1[j], fmaf(d1, w1[64 + j], b1[j]));
        float x2 = x * x;
        float zn = x * fmaf(x2, -0.07135481f, -1.5957692f);
        float e  = __expf(zn);
        float h  = x * __builtin_amdgcn_rcpf(1.0f + e);
        f32x2 hv = {h, h};
        const f32x2* w2r = (const f32x2*)&w2[j * CH];
        #pragma unroll
        for (int i = 0; i < 4; ++i) acc[i] += hv * w2r[i];
    }
    long qk = (long)q * CNC + kk;
    #pragma unroll
    for (int hh = 0; hh < CH; ++hh)
        bias[(long)(b * CH + hh) * CNQ * CNC + qk] = __float2bfloat16(acc[hh >> 1][hh & 1]);
}

// ---------------- row softmax in place: f32 row -> bf16 row (written over row start) ----------------
template<int NPT>
__global__ __launch_bounds__(256) void softmax_kernel(float* __restrict__ S, long ld) {
    __shared__ float red[8];
    long row = blockIdx.x;
    float* base = S + row * ld;
    int t = threadIdx.x;
    const int c0 = t * NPT;
    float v[NPT];
    #pragma unroll
    for (int i = 0; i < NPT; ++i) v[i] = base[c0 + i];
    float m = v[0];
    #pragma unroll
    for (int i = 1; i < NPT; ++i) m = fmaxf(m, v[i]);
    #pragma unroll
    for (int o = 32; o; o >>= 1) m = fmaxf(m, __shfl_xor(m, o));
    if ((t & 63) == 0) red[t >> 6] = m;
    __syncthreads();                      // also guarantees all loads done before bf16 writes
    m = fmaxf(fmaxf(red[0], red[1]), fmaxf(red[2], red[3]));
    float s = 0.0f;
    #pragma unroll
    for (int i = 0; i < NPT; ++i) { v[i] = __expf(v[i] - m); s += v[i]; }
    #pragma unroll
    for (int o = 32; o; o >>= 1) s += __shfl_xor(s, o);
    __syncthreads();
    if ((t & 63) == 0) red[4 + (t >> 6)] = s;
    __syncthreads();
    s = red[4] + red[5] + red[6] + red[7];
    float inv = 1.0f / s;
    bf16_t* ob = (bf16_t*)base;
    #pragma unroll
    for (int i = 0; i < NPT; ++i) ob[c0 + i] = __float2bfloat16(v[i] * inv);
}

// ---------------- generic NT MFMA GEMM: C[z] = scale*(A[z] @ Bt[z]^T) + epilogue ----------------
// A: M x K row-major bf16 (ldA elems). Bt: N x K row-major bf16 (row n = column n of B).
// OUT: 0 f32 plain, 1 bf16 plain, 2 bf16 head-split (B,H,NR,HD), 3 bf16 head-split-T (B,H,HD,NR),
//      4 bf16 merge96: z=(b,h), write (b, row, h*HD+col) into (B,NQ,D).
template<int MF, int NF, int BK, int OUT, bool BIAS, bool B2D, bool GELU_E, bool RES>
__global__ __launch_bounds__(256) void gemm_nt(
        const bf16_t* __restrict__ A, long ldA, long zsA,
        const bf16_t* __restrict__ Bt, long ldB, long zsB,
        const float* __restrict__ bias,
        const bf16_t* __restrict__ b2d, long zs2d, long ld2d,
        const float* __restrict__ res,
        void* __restrict__ Cout, long ldC, long zsC,
        int K, int NR, float scale) {
    constexpr int BM = MF * 32, BN = NF * 32;
    constexpr int PAD = 4, LDT = BK + PAD;   // stride mod 32 = 4 words: conflict-free b128 r/w
    constexpr int SEGS = BK / 8;
    static_assert((BM * SEGS) % 256 == 0 && (BN * SEGS) % 256 == 0, "staging divisibility");
    __shared__ __bf16 As[BM * LDT];
    __shared__ __bf16 Bs[BN * LDT];
    const int tid = threadIdx.x;
    const int z = blockIdx.z;
    const int m0 = blockIdx.y * BM, n0 = blockIdx.x * BN;
    const bf16_t* Ab = A + (long)z * zsA + (long)m0 * ldA;
    const bf16_t* Bb = Bt + (long)z * zsB + (long)n0 * ldB;
    const int w = tid >> 6, lane = tid & 63;
    const int wm = w >> 1, wn = w & 1;
    const int l15 = lane & 15, l4 = lane >> 4;
    f32x4 acc[MF][NF] = {};
    for (int k0 = 0; k0 < K; k0 += BK) {
        #pragma unroll
        for (int it = 0; it < (BM * SEGS) / 256; ++it) {
            int c = tid + it * 256;
            int r = c / SEGS, sg = c % SEGS;
            *(bf16x8*)&As[r * LDT + sg * 8] = *(const bf16x8*)&Ab[(long)r * ldA + k0 + sg * 8];
        }
        #pragma unroll
        for (int it = 0; it < (BN * SEGS) / 256; ++it) {
            int c = tid + it * 256;
            int r = c / SEGS, sg = c % SEGS;
            *(bf16x8*)&Bs[r * LDT + sg * 8] = *(const bf16x8*)&Bb[(long)r * ldB + k0 + sg * 8];
        }
        __syncthreads();
        #pragma unroll
        for (int s = 0; s < BK / 32; ++s) {
            bf16x8 af[MF], bfr[NF];
            #pragma unroll
            for (int i = 0; i < MF; ++i)
                af[i] = *(const bf16x8*)&As[(wm * MF * 16 + i * 16 + l15) * LDT + s * 32 + l4 * 8];
            #pragma unroll
            for (int j = 0; j < NF; ++j)
                bfr[j] = *(const bf16x8*)&Bs[(wn * NF * 16 + j * 16 + l15) * LDT + s * 32 + l4 * 8];
            #pragma unroll
            for (int i = 0; i < MF; ++i)
                #pragma unroll
                for (int j = 0; j < NF; ++j)
                    acc[i][j] = __builtin_amdgcn_mfma_f32_16x16x32_bf16(af[i], bfr[j], acc[i][j], 0, 0, 0);
        }
        __syncthreads();
    }
    #pragma unroll
    for (int i = 0; i < MF; ++i) {
        const int rbase = m0 + wm * MF * 16 + i * 16 + l4 * 4;
        #pragma unroll
        for (int j = 0; j < NF; ++j) {
            const int col = n0 + wn * NF * 16 + j * 16 + l15;
            #pragma unroll
            for (int r = 0; r < 4; ++r) {
                int row = rbase + r;
                float v = acc[i][j][r] * scale;
                if constexpr (BIAS) v += bias[col];
                if constexpr (B2D)  v += __bfloat162float(b2d[(long)z * zs2d + (long)row * ld2d + col]);
                if constexpr (GELU_E) v = gelu_f(v);
                if constexpr (RES)  v += res[(long)row * ldC + col];
                if constexpr (OUT == 0) {
                    ((float*)Cout)[(long)z * zsC + (long)row * ldC + col] = v;
                } else if constexpr (OUT == 1) {
                    ((bf16_t*)Cout)[(long)z * zsC + (long)row * ldC + col] = __float2bfloat16(v);
                } else if constexpr (OUT == 2) {
                    int bb = row / NR, n = row - bb * NR;
                    int hh = col / CHD, dd = col - hh * CHD;
                    ((bf16_t*)Cout)[((long)(bb * CH + hh) * NR + n) * CHD + dd] = __float2bfloat16(v);
                } else if constexpr (OUT == 3) {
                    int bb = row / NR, n = row - bb * NR;
                    int hh = col / CHD, dd = col - hh * CHD;
                    ((bf16_t*)Cout)[((long)(bb * CH + hh) * CHD + dd) * NR + n] = __float2bfloat16(v);
                } else { // OUT == 4
                    int bb = z / CH, hh = z - bb * CH;
                    ((bf16_t*)Cout)[((long)bb * CNQ + row) * CD + hh * CHD + col] = __float2bfloat16(v);
                }
            }
        }
    }
}

extern "C" void kernel_launch(void* const* d_in, const int* in_sizes, int n_in,
                              void* d_out, int out_size, void* d_ws, size_t ws_size,
                              hipStream_t stream) {
    const float* query_state    = (const float*)d_in[0];
    const float* context_k      = (const float*)d_in[1];
    const float* context_v      = (const float*)d_in[2];
    const float* query_coords   = (const float*)d_in[3];
    const float* context_coords = (const float*)d_in[4];
    const float* sn_g = (const float*)d_in[5];  const float* sn_b = (const float*)d_in[6];
    const float* sa_wq = (const float*)d_in[7];  const float* sa_bq = (const float*)d_in[8];
    const float* sa_wk = (const float*)d_in[9];  const float* sa_bk = (const float*)d_in[10];
    const float* sa_wv = (const float*)d_in[11]; const float* sa_bv = (const float*)d_in[12];
    const float* sa_wo = (const float*)d_in[13]; const float* sa_bo = (const float*)d_in[14];
    const float* cn_g = (const float*)d_in[15];  const float* cn_b = (const float*)d_in[16];
    const float* ca_wq = (const float*)d_in[17]; const float* ca_bq = (const float*)d_in[18];
    const float* ca_wk = (const float*)d_in[19]; const float* ca_bk = (const float*)d_in[20];
    const float* ca_wv = (const float*)d_in[21]; const float* ca_bv = (const float*)d_in[22];
    const float* ca_wo = (const float*)d_in[23]; const float* ca_bo = (const float*)d_in[24];
    const float* rb_w1 = (const float*)d_in[25]; const float* rb_b1 = (const float*)d_in[26];
    const float* rb_w2 = (const float*)d_in[27]; const float* rb_b2 = (const float*)d_in[28];
    const float* fn_g = (const float*)d_in[29];  const float* fn_b = (const float*)d_in[30];
    const float* ffn_w1 = (const float*)d_in[31]; const float* ffn_b1 = (const float*)d_in[32];
    const float* ffn_w2 = (const float*)d_in[33]; const float* ffn_b2 = (const float*)d_in[34];
    float* out = (float*)d_out;

    char* p = (char*)d_ws;
    auto alloc = [&](size_t bytes) -> char* {
        char* r = p; p += (bytes + 255) & ~(size_t)255; return r;
    };
    const size_t WDD = (size_t)CD * CD, WDF = (size_t)CD * CFFN;
    bf16_t* sa_wq_t = (bf16_t*)alloc(WDD * 2);
    bf16_t* sa_wk_t = (bf16_t*)alloc(WDD * 2);
    bf16_t* sa_wv_t = (bf16_t*)alloc(WDD * 2);
    bf16_t* sa_wo_t = (bf16_t*)alloc(WDD * 2);
    bf16_t* ca_wq_t = (bf16_t*)alloc(WDD * 2);
    bf16_t* ca_wk_t = (bf16_t*)alloc(WDD * 2);
    bf16_t* ca_wv_t = (bf16_t*)alloc(WDD * 2);
    bf16_t* ca_wo_t = (bf16_t*)alloc(WDD * 2);
    bf16_t* ffn_w1_t = (bf16_t*)alloc(WDF * 2);
    bf16_t* ffn_w2_t = (bf16_t*)alloc(WDF * 2);
    bf16_t* ln_buf   = (bf16_t*)alloc((size_t)CB * CNQ * CD * 2);
    bf16_t* q_split  = (bf16_t*)alloc((size_t)CB * CH * CNQ * CHD * 2);
    bf16_t* k_split  = (bf16_t*)alloc((size_t)CB * CH * CNQ * CHD * 2);
    bf16_t* v_splitT = (bf16_t*)alloc((size_t)CB * CH * CNQ * CHD * 2);
    bf16_t* ck_b     = (bf16_t*)alloc((size_t)CB * CNC * CD * 2);
    bf16_t* cv_b     = (bf16_t*)alloc((size_t)CB * CNC * CD * 2);
    bf16_t* kc_split = (bf16_t*)alloc((size_t)CB * CH * CNC * CHD * 2);
    bf16_t* vc_splitT= (bf16_t*)alloc((size_t)CB * CH * CNC * CHD * 2);
    float*  S        = (float*)alloc((size_t)CB * CH * CNQ * CNC * 4);
    bf16_t* bias2d   = (bf16_t*)alloc((size_t)CB * CH * CNQ * CNC * 2);
    bf16_t* attn_m   = (bf16_t*)alloc((size_t)CB * CNQ * CD * 2);
    float*  xbuf     = (float*)alloc((size_t)CB * CNQ * CD * 4);
    bf16_t* ffn_h    = (bf16_t*)alloc((size_t)CB * CNQ * CFFN * 2);

    const dim3 tb(256);
    const float qk_scale = 0.10206207261596575f;  // 96^-0.5

    // weights -> bf16 transposed
    wtrans_kernel<<<dim3(CD / 32, CD / 32), tb, 0, stream>>>(sa_wq, sa_wq_t, CD, CD);
    wtrans_kernel<<<dim3(CD / 32, CD / 32), tb, 0, stream>>>(sa_wk, sa_wk_t, CD, CD);
    wtrans_kernel<<<dim3(CD / 32, CD / 32), tb, 0, stream>>>(sa_wv, sa_wv_t, CD, CD);
    wtrans_kernel<<<dim3(CD / 32, CD / 32), tb, 0, stream>>>(sa_wo, sa_wo_t, CD, CD);
    wtrans_kernel<<<dim3(CD / 32, CD / 32), tb, 0, stream>>>(ca_wq, ca_wq_t, CD, CD);
    wtrans_kernel<<<dim3(CD / 32, CD / 32), tb, 0, stream>>>(ca_wk, ca_wk_t, CD, CD);
    wtrans_kernel<<<dim3(CD / 32, CD / 32), tb, 0, stream>>>(ca_wv, ca_wv_t, CD, CD);
    wtrans_kernel<<<dim3(CD / 32, CD / 32), tb, 0, stream>>>(ca_wo, ca_wo_t, CD, CD);
    wtrans_kernel<<<dim3(CFFN / 32, CD / 32), tb, 0, stream>>>(ffn_w1, ffn_w1_t, CD, CFFN);
    wtrans_kernel<<<dim3(CD / 32, CFFN / 32), tb, 0, stream>>>(ffn_w2, ffn_w2_t, CFFN, CD);
    // context k/v -> bf16
    cvt_kernel<<<(CB * CNC * CD) / 1024, tb, 0, stream>>>(context_k, ck_b, (long)CB * CNC * CD);
    cvt_kernel<<<(CB * CNC * CD) / 1024, tb, 0, stream>>>(context_v, cv_b, (long)CB * CNC * CD);
    // relative coordinate bias
    relbias_kernel<<<(CB * CNQ * CNC) / 256, tb, 0, stream>>>(query_coords, context_coords,
                                                              rb_w1, rb_b1, rb_w2, rb_b2, bias2d);
    // ---- self attention ----
    ln_kernel<<<CB * CNQ, tb, 0, stream>>>(query_state, sn_g, sn_b, ln_buf);
    gemm_nt<2,2,64,2,true,false,false,false><<<dim3(CD / 64, (CB * CNQ) / 64, 1), tb, 0, stream>>>(
        ln_buf, CD, 0, sa_wq_t, CD, 0, sa_bq, nullptr, 0, 0, nullptr, q_split, 0, 0, CD, CNQ, 1.0f);
    gemm_nt<2,2,64,2,true,false,false,false><<<dim3(CD / 64, (CB * CNQ) / 64, 1), tb, 0, stream>>>(
        ln_buf, CD, 0, sa_wk_t, CD, 0, sa_bk, nullptr, 0, 0, nullptr, k_split, 0, 0, CD, CNQ, 1.0f);
    gemm_nt<2,2,64,3,true,false,false,false><<<dim3(CD / 64, (CB * CNQ) / 64, 1), tb, 0, stream>>>(
        ln_buf, CD, 0, sa_wv_t, CD, 0, sa_bv, nullptr, 0, 0, nullptr, v_splitT, 0, 0, CD, CNQ, 1.0f);
    gemm_nt<4,2,96,0,false,false,false,false><<<dim3(CNQ / 64, CNQ / 128, CB * CH), tb, 0, stream>>>(
        q_split, CHD, (long)CNQ * CHD, k_split, CHD, (long)CNQ * CHD,
        nullptr, nullptr, 0, 0, nullptr, S, CNQ, (long)CNQ * CNQ, CHD, 0, qk_scale);
    softmax_kernel<2><<<CB * CH * CNQ, tb, 0, stream>>>(S, CNQ);
    gemm_nt<2,3,64,4,false,false,false,false><<<dim3(1, CNQ / 64, CB * CH), tb, 0, stream>>>(
        (const bf16_t*)S, 2 * CNQ, (long)CNQ * 2 * CNQ, v_splitT, CNQ, (long)CHD * CNQ,
        nullptr, nullptr, 0, 0, nullptr, attn_m, 0, 0, CNQ, CNQ, 1.0f);
    gemm_nt<2,2,64,0,true,false,false,true><<<dim3(CD / 64, (CB * CNQ) / 64, 1), tb, 0, stream>>>(
        attn_m, CD, 0, sa_wo_t, CD, 0, sa_bo, nullptr, 0, 0, query_state, xbuf, CD, 0, CD, 0, 1.0f);
    // ---- cross attention ----
    ln_kernel<<<CB * CNQ, tb, 0, stream>>>(xbuf, cn_g, cn_b, ln_buf);
    gemm_nt<2,2,64,2,true,false,false,false><<<dim3(CD / 64, (CB * CNQ) / 64, 1), tb, 0, stream>>>(
        ln_buf, CD, 0, ca_wq_t, CD, 0, ca_bq, nullptr, 0, 0, nullptr, q_split, 0, 0, CD, CNQ, 1.0f);
    gemm_nt<4,4,64,2,true,false,false,false><<<dim3(CD / 128, (CB * CNC) / 128, 1), tb, 0, stream>>>(
        ck_b, CD, 0, ca_wk_t, CD, 0, ca_bk, nullptr, 0, 0, nullptr, kc_split, 0, 0, CD, CNC, 1.0f);
    gemm_nt<4,4,64,3,true,false,false,false><<<dim3(CD / 128, (CB * CNC) / 128, 1), tb, 0, stream>>>(
        cv_b, CD, 0, ca_wv_t, CD, 0, ca_bv, nullptr, 0, 0, nullptr, vc_splitT, 0, 0, CD, CNC, 1.0f);
    gemm_nt<4,2,96,0,false,true,false,false><<<dim3(CNC / 64, CNQ / 128, CB * CH), tb, 0, stream>>>(
        q_split, CHD, (long)CNQ * CHD, kc_split, CHD, (long)CNC * CHD,
        nullptr, bias2d, (long)CNQ * CNC, CNC, nullptr, S, CNC, (long)CNQ * CNC, CHD, 0, qk_scale);
    softmax_kernel<8><<<CB * CH * CNQ, tb, 0, stream>>>(S, CNC);
    gemm_nt<2,3,64,4,false,false,false,false><<<dim3(1, CNQ / 64, CB * CH), tb, 0, stream>>>(
        (const bf16_t*)S, 2 * CNC, (long)CNQ * 2 * CNC, vc_splitT, CNC, (long)CHD * CNC,
        nullptr, nullptr, 0, 0, nullptr, attn_m, 0, 0, CNC, CNQ, 1.0f);
    gemm_nt<2,2,64,0,true,false,false,true><<<dim3(CD / 64, (CB * CNQ) / 64, 1), tb, 0, stream>>>(
        attn_m, CD, 0, ca_wo_t, CD, 0, ca_bo, nullptr, 0, 0, xbuf, xbuf, CD, 0, CD, 0, 1.0f);
    // ---- FFN ----
    ln_kernel<<<CB * CNQ, tb, 0, stream>>>(xbuf, fn_g, fn_b, ln_buf);
    gemm_nt<4,4,64,1,true,false,true,false><<<dim3(CFFN / 128, (CB * CNQ) / 128, 1), tb, 0, stream>>>(
        ln_buf, CD, 0, ffn_w1_t, CD, 0, ffn_b1, nullptr, 0, 0, nullptr, ffn_h, CFFN, 0, CD, 0, 1.0f);
    gemm_nt<2,2,64,0,true,false,false,true><<<dim3(CD / 64, (CB * CNQ) / 64, 1), tb, 0, stream>>>(
        ffn_h, CFFN, 0, ffn_w2_t, CFFN, 0, ffn_b2, nullptr, 0, 0, xbuf, out, CD, 0, CFFN, 0, 1.0f);
}

// Round 8
// 485.842 us; speedup vs baseline: 1.1259x; 1.0625x over previous
//
#include <hip/hip_runtime.h>
#include <hip/hip_bf16.h>

typedef __bf16 bf16x8 __attribute__((ext_vector_type(8)));
typedef float  f32x4  __attribute__((ext_vector_type(4)));
typedef float  f32x2  __attribute__((ext_vector_type(2)));
typedef __hip_bfloat16 bf16_t;

constexpr int CB  = 2;
constexpr int CNQ = 512;
constexpr int CNC = 2048;
constexpr int CD  = 768;
constexpr int CH  = 8;
constexpr int CHD = 96;
constexpr int CFFN = 3072;

// fast gelu: x * sigmoid(1.5957692(x + 0.044715 x^3)); max abs err vs exact ~3e-4
static __device__ __forceinline__ float gelu_f(float x) {
    float x2 = x * x;
    float zn = x * fmaf(x2, -0.07135481f, -1.5957692f);
    float e  = __expf(zn);
    return x * __builtin_amdgcn_rcpf(1.0f + e);
}

// ---------------- LayerNorm: f32 in -> bf16 out, one block per row (D=768) ----------------
__global__ __launch_bounds__(256) void ln_kernel(const float* __restrict__ x,
                                                 const float* __restrict__ g,
                                                 const float* __restrict__ b,
                                                 bf16_t* __restrict__ out) {
    __shared__ float red[8];
    long row = blockIdx.x;
    const float* xr = x + row * CD;
    int t = threadIdx.x;
    float v0 = xr[t], v1 = xr[t + 256], v2 = xr[t + 512];
    float s  = v0 + v1 + v2;
    float sq = v0 * v0 + v1 * v1 + v2 * v2;
    #pragma unroll
    for (int o = 32; o; o >>= 1) { s += __shfl_xor(s, o); sq += __shfl_xor(sq, o); }
    if ((t & 63) == 0) { red[t >> 6] = s; red[4 + (t >> 6)] = sq; }
    __syncthreads();
    s  = red[0] + red[1] + red[2] + red[3];
    sq = red[4] + red[5] + red[6] + red[7];
    float mean = s * (1.0f / 768.0f);
    float var  = sq * (1.0f / 768.0f) - mean * mean;
    float inv  = rsqrtf(var + 1e-5f);
    bf16_t* orow = out + row * CD;
    orow[t]       = __float2bfloat16((v0 - mean) * inv * g[t]       + b[t]);
    orow[t + 256] = __float2bfloat16((v1 - mean) * inv * g[t + 256] + b[t + 256]);
    orow[t + 512] = __float2bfloat16((v2 - mean) * inv * g[t + 512] + b[t + 512]);
}

// ---------------- batched 8x weight transpose 768x768 f32 -> bf16 T ----------------
__global__ __launch_bounds__(256) void wtrans8_kernel(
        const float* W0, const float* W1, const float* W2, const float* W3,
        const float* W4, const float* W5, const float* W6, const float* W7,
        bf16_t* T0, bf16_t* T1, bf16_t* T2, bf16_t* T3,
        bf16_t* T4, bf16_t* T5, bf16_t* T6, bf16_t* T7) {
    const float* Ws[8] = {W0, W1, W2, W3, W4, W5, W6, W7};
    bf16_t*      Ts[8] = {T0, T1, T2, T3, T4, T5, T6, T7};
    const float* W = Ws[blockIdx.z];
    bf16_t*      T = Ts[blockIdx.z];
    __shared__ float tile[32][33];
    int tx = threadIdx.x & 31, ty = threadIdx.x >> 5;
    int bx = blockIdx.x, by = blockIdx.y;
    #pragma unroll
    for (int i = 0; i < 4; ++i)
        tile[ty + i * 8][tx] = W[(long)(by * 32 + ty + i * 8) * CD + bx * 32 + tx];
    __syncthreads();
    #pragma unroll
    for (int i = 0; i < 4; ++i)
        T[(long)(bx * 32 + ty + i * 8) * CD + by * 32 + tx] = __float2bfloat16(tile[tx][ty + i * 8]);
}

// ---------------- generic weight transpose: W (K x N) f32 -> Wt (N x K) bf16 ----------------
__global__ __launch_bounds__(256) void wtrans_kernel(const float* __restrict__ W,
                                                     bf16_t* __restrict__ Wt, int K, int N) {
    __shared__ float tile[32][33];
    int tx = threadIdx.x & 31, ty = threadIdx.x >> 5;
    int bx = blockIdx.x, by = blockIdx.y;
    #pragma unroll
    for (int i = 0; i < 4; ++i) {
        int k = by * 32 + ty + i * 8;
        tile[ty + i * 8][tx] = W[(long)k * N + bx * 32 + tx];
    }
    __syncthreads();
    #pragma unroll
    for (int i = 0; i < 4; ++i) {
        int n = bx * 32 + ty + i * 8;
        Wt[(long)n * K + by * 32 + tx] = __float2bfloat16(tile[tx][ty + i * 8]);
    }
}

// ---------------- concat 3 x 768 f32 biases -> 2304 ----------------
__global__ __launch_bounds__(256) void biascat_kernel(const float* __restrict__ b0,
                                                      const float* __restrict__ b1,
                                                      const float* __restrict__ b2,
                                                      float* __restrict__ out) {
    int i = blockIdx.x * 256 + threadIdx.x;   // 0..2303
    float v = i < 768 ? b0[i] : (i < 1536 ? b1[i - 768] : b2[i - 1536]);
    out[i] = v;
}

// ---------------- relative coordinate bias -> (B,H,NQ,NC) bf16 ----------------
__global__ __launch_bounds__(256) void relbias_kernel(const float* __restrict__ qc,
                                                      const float* __restrict__ cc,
                                                      const float* __restrict__ w1,
                                                      const float* __restrict__ b1,
                                                      const float* __restrict__ w2,
                                                      const float* __restrict__ b2,
                                                      bf16_t* __restrict__ bias) {
    long idx = (long)blockIdx.x * 256 + threadIdx.x;   // over B*NQ*NC
    int  kk = (int)(idx & (CNC - 1));
    long t2 = idx >> 11;
    int  q  = (int)(t2 & (CNQ - 1));
    int  b  = (int)(t2 >> 9);
    float d0 = qc[((long)b * CNQ + q) * 2]     - cc[((long)b * CNC + kk) * 2];
    float d1 = qc[((long)b * CNQ + q) * 2 + 1] - cc[((long)b * CNC + kk) * 2 + 1];
    f32x2 acc[4];
    #pragma unroll
    for (int i = 0; i < 4; ++i) { acc[i][0] = b2[2 * i]; acc[i][1] = b2[2 * i + 1]; }
    #pragma unroll 8
    for (int j = 0; j < 64; ++j) {
        float x = fmaf(d0, w1[j], fmaf(d1, w1[64 + j], b1[j]));
        float x2 = x * x;
        float zn = x * fmaf(x2, -0.07135481f, -1.5957692f);
        float e  = __expf(zn);
        float h  = x * __builtin_amdgcn_rcpf(1.0f + e);
        f32x2 hv = {h, h};
        const f32x2* w2r = (const f32x2*)&w2[j * CH];
        #pragma unroll
        for (int i = 0; i < 4; ++i) acc[i] += hv * w2r[i];
    }
    long qk = (long)q * CNC + kk;
    #pragma unroll
    for (int hh = 0; hh < CH; ++hh)
        bias[(long)(b * CH + hh) * CNQ * CNC + qk] = __float2bfloat16(acc[hh >> 1][hh & 1]);
}

// ---------------- row softmax in place: f32 row -> bf16 row ----------------
template<int NPT>
__global__ __launch_bounds__(256) void softmax_kernel(float* __restrict__ S, long ld) {
    __shared__ float red[8];
    long row = blockIdx.x;
    float* base = S + row * ld;
    int t = threadIdx.x;
    const int c0 = t * NPT;
    float v[NPT];
    #pragma unroll
    for (int i = 0; i < NPT; ++i) v[i] = base[c0 + i];
    float m = v[0];
    #pragma unroll
    for (int i = 1; i < NPT; ++i) m = fmaxf(m, v[i]);
    #pragma unroll
    for (int o = 32; o; o >>= 1) m = fmaxf(m, __shfl_xor(m, o));
    if ((t & 63) == 0) red[t >> 6] = m;
    __syncthreads();
    m = fmaxf(fmaxf(red[0], red[1]), fmaxf(red[2], red[3]));
    float s = 0.0f;
    #pragma unroll
    for (int i = 0; i < NPT; ++i) { v[i] = __expf(v[i] - m); s += v[i]; }
    #pragma unroll
    for (int o = 32; o; o >>= 1) s += __shfl_xor(s, o);
    __syncthreads();
    if ((t & 63) == 0) red[4 + (t >> 6)] = s;
    __syncthreads();
    s = red[4] + red[5] + red[6] + red[7];
    float inv = 1.0f / s;
    bf16_t* ob = (bf16_t*)base;
    #pragma unroll
    for (int i = 0; i < NPT; ++i) ob[c0 + i] = __float2bfloat16(v[i] * inv);
}

// ---------------- generic NT MFMA GEMM ----------------
// OUT: 0 f32 plain, 1 bf16 plain, 2 bf16 head-split (B,H,NR,HD), 3 bf16 head-split-T (B,H,HD,NR),
//      4 bf16 merge96 (z=(b,h)), 5 fused-QKV split writer (q/k normal, v transposed).
// AF32: A is f32, converted to bf16 during LDS staging.
template<int MF, int NF, int BK, int OUT, bool BIAS, bool B2D, bool GELU_E, bool RES, bool AF32 = false>
__global__ __launch_bounds__(256) void gemm_nt(
        const void* __restrict__ Araw, long ldA, long zsA,
        const bf16_t* __restrict__ Bt, long ldB, long zsB,
        const float* __restrict__ bias,
        const bf16_t* __restrict__ b2d, long zs2d, long ld2d,
        const float* __restrict__ res,
        void* __restrict__ Cout, long ldC, long zsC,
        int K, int NR, float scale) {
    constexpr int BM = MF * 32, BN = NF * 32;
    constexpr int PAD = 4, LDT = BK + PAD;   // stride mod 32 = 4 words: conflict-free b128 r/w
    constexpr int SEGS = BK / 8;
    static_assert((BN * SEGS) % 256 == 0, "B staging divisibility");
    __shared__ __bf16 As[BM * LDT];
    __shared__ __bf16 Bs[BN * LDT];
    const int tid = threadIdx.x;
    const int z = blockIdx.z;
    const int m0 = blockIdx.y * BM, n0 = blockIdx.x * BN;
    const bf16_t* Ab = nullptr; const float* Af = nullptr;
    if constexpr (AF32) Af = (const float*)Araw + (long)z * zsA + (long)m0 * ldA;
    else                Ab = (const bf16_t*)Araw + (long)z * zsA + (long)m0 * ldA;
    const bf16_t* Bb = Bt + (long)z * zsB + (long)n0 * ldB;
    const int w = tid >> 6, lane = tid & 63;
    const int wm = w >> 1, wn = w & 1;
    const int l15 = lane & 15, l4 = lane >> 4;
    f32x4 acc[MF][NF] = {};
    for (int k0 = 0; k0 < K; k0 += BK) {
        if constexpr (AF32) {
            constexpr int SEGA = BK / 4;
            static_assert((BM * SEGA) % 256 == 0, "A f32 staging divisibility");
            #pragma unroll
            for (int it = 0; it < (BM * SEGA) / 256; ++it) {
                int c = tid + it * 256;
                int r = c / SEGA, sg = c % SEGA;
                float4 v = *(const float4*)&Af[(long)r * ldA + k0 + sg * 4];
                union { bf16_t b[4]; uint2 u; } cv;
                cv.b[0] = __float2bfloat16(v.x); cv.b[1] = __float2bfloat16(v.y);
                cv.b[2] = __float2bfloat16(v.z); cv.b[3] = __float2bfloat16(v.w);
                *(uint2*)&As[r * LDT + sg * 4] = cv.u;
            }
        } else {
            static_assert((BM * SEGS) % 256 == 0 || AF32, "A staging divisibility");
            #pragma unroll
            for (int it = 0; it < (BM * SEGS) / 256; ++it) {
                int c = tid + it * 256;
                int r = c / SEGS, sg = c % SEGS;
                *(bf16x8*)&As[r * LDT + sg * 8] = *(const bf16x8*)&Ab[(long)r * ldA + k0 + sg * 8];
            }
        }
        #pragma unroll
        for (int it = 0; it < (BN * SEGS) / 256; ++it) {
            int c = tid + it * 256;
            int r = c / SEGS, sg = c % SEGS;
            *(bf16x8*)&Bs[r * LDT + sg * 8] = *(const bf16x8*)&Bb[(long)r * ldB + k0 + sg * 8];
        }
        __syncthreads();
        #pragma unroll
        for (int s = 0; s < BK / 32; ++s) {
            bf16x8 af[MF], bfr[NF];
            #pragma unroll
            for (int i = 0; i < MF; ++i)
                af[i] = *(const bf16x8*)&As[(wm * MF * 16 + i * 16 + l15) * LDT + s * 32 + l4 * 8];
            #pragma unroll
            for (int j = 0; j < NF; ++j)
                bfr[j] = *(const bf16x8*)&Bs[(wn * NF * 16 + j * 16 + l15) * LDT + s * 32 + l4 * 8];
            #pragma unroll
            for (int i = 0; i < MF; ++i)
                #pragma unroll
                for (int j = 0; j < NF; ++j)
                    acc[i][j] = __builtin_amdgcn_mfma_f32_16x16x32_bf16(af[i], bfr[j], acc[i][j], 0, 0, 0);
        }
        __syncthreads();
    }
    #pragma unroll
    for (int i = 0; i < MF; ++i) {
        const int rbase = m0 + wm * MF * 16 + i * 16 + l4 * 4;
        #pragma unroll
        for (int j = 0; j < NF; ++j) {
            const int col = n0 + wn * NF * 16 + j * 16 + l15;
            #pragma unroll
            for (int r = 0; r < 4; ++r) {
                int row = rbase + r;
                float v = acc[i][j][r] * scale;
                if constexpr (BIAS) v += bias[col];
                if constexpr (B2D)  v += __bfloat162float(b2d[(long)z * zs2d + (long)row * ld2d + col]);
                if constexpr (GELU_E) v = gelu_f(v);
                if constexpr (RES)  v += res[(long)row * ldC + col];
                if constexpr (OUT == 0) {
                    ((float*)Cout)[(long)z * zsC + (long)row * ldC + col] = v;
                } else if constexpr (OUT == 1) {
                    ((bf16_t*)Cout)[(long)z * zsC + (long)row * ldC + col] = __float2bfloat16(v);
                } else if constexpr (OUT == 2) {
                    int bb = row / NR, n = row - bb * NR;
                    int hh = col / CHD, dd = col - hh * CHD;
                    ((bf16_t*)Cout)[((long)(bb * CH + hh) * NR + n) * CHD + dd] = __float2bfloat16(v);
                } else if constexpr (OUT == 3) {
                    int bb = row / NR, n = row - bb * NR;
                    int hh = col / CHD, dd = col - hh * CHD;
                    ((bf16_t*)Cout)[((long)(bb * CH + hh) * CHD + dd) * NR + n] = __float2bfloat16(v);
                } else if constexpr (OUT == 4) {
                    int bb = z / CH, hh = z - bb * CH;
                    ((bf16_t*)Cout)[((long)bb * CNQ + row) * CD + hh * CHD + col] = __float2bfloat16(v);
                } else { // OUT == 5: fused QKV, col in [0,2304), Cout = qkv split base
                    constexpr long QSZ5 = (long)CB * CH * CNQ * CHD;
                    int part = col / CD;            // 0=q 1=k 2=v
                    int c = col - part * CD;
                    int hh = c / CHD, dd = c - hh * CHD;
                    int bb = row / CNQ, n = row - bb * CNQ;
                    long off;
                    if (part == 0)      off = ((long)(bb * CH + hh) * CNQ + n) * CHD + dd;
                    else if (part == 1) off = QSZ5 + ((long)(bb * CH + hh) * CNQ + n) * CHD + dd;
                    else                off = 2 * QSZ5 + ((long)(bb * CH + hh) * CHD + dd) * CNQ + n;
                    ((bf16_t*)Cout)[off] = __float2bfloat16(v);
                }
            }
        }
    }
}

extern "C" void kernel_launch(void* const* d_in, const int* in_sizes, int n_in,
                              void* d_out, int out_size, void* d_ws, size_t ws_size,
                              hipStream_t stream) {
    const float* query_state    = (const float*)d_in[0];
    const float* context_k      = (const float*)d_in[1];
    const float* context_v      = (const float*)d_in[2];
    const float* query_coords   = (const float*)d_in[3];
    const float* context_coords = (const float*)d_in[4];
    const float* sn_g = (const float*)d_in[5];  const float* sn_b = (const float*)d_in[6];
    const float* sa_wq = (const float*)d_in[7];  const float* sa_bq = (const float*)d_in[8];
    const float* sa_wk = (const float*)d_in[9];  const float* sa_bk = (const float*)d_in[10];
    const float* sa_wv = (const float*)d_in[11]; const float* sa_bv = (const float*)d_in[12];
    const float* sa_wo = (const float*)d_in[13]; const float* sa_bo = (const float*)d_in[14];
    const float* cn_g = (const float*)d_in[15];  const float* cn_b = (const float*)d_in[16];
    const float* ca_wq = (const float*)d_in[17]; const float* ca_bq = (const float*)d_in[18];
    const float* ca_wk = (const float*)d_in[19]; const float* ca_bk = (const float*)d_in[20];
    const float* ca_wv = (const float*)d_in[21]; const float* ca_bv = (const float*)d_in[22];
    const float* ca_wo = (const float*)d_in[23]; const float* ca_bo = (const float*)d_in[24];
    const float* rb_w1 = (const float*)d_in[25]; const float* rb_b1 = (const float*)d_in[26];
    const float* rb_w2 = (const float*)d_in[27]; const float* rb_b2 = (const float*)d_in[28];
    const float* fn_g = (const float*)d_in[29];  const float* fn_b = (const float*)d_in[30];
    const float* ffn_w1 = (const float*)d_in[31]; const float* ffn_b1 = (const float*)d_in[32];
    const float* ffn_w2 = (const float*)d_in[33]; const float* ffn_b2 = (const float*)d_in[34];
    float* out = (float*)d_out;

    char* p = (char*)d_ws;
    auto alloc = [&](size_t bytes) -> char* {
        char* r = p; p += (bytes + 255) & ~(size_t)255; return r;
    };
    const size_t WDD = (size_t)CD * CD, WDF = (size_t)CD * CFFN;
    const size_t QSZ = (size_t)CB * CH * CNQ * CHD;
    bf16_t* qkv_wt  = (bf16_t*)alloc(3 * WDD * 2);          // [wq^T | wk^T | wv^T]
    bf16_t* sa_wo_t = (bf16_t*)alloc(WDD * 2);
    bf16_t* ca_wq_t = (bf16_t*)alloc(WDD * 2);
    bf16_t* ca_wk_t = (bf16_t*)alloc(WDD * 2);
    bf16_t* ca_wv_t = (bf16_t*)alloc(WDD * 2);
    bf16_t* ca_wo_t = (bf16_t*)alloc(WDD * 2);
    bf16_t* ffn_w1_t = (bf16_t*)alloc(WDF * 2);
    bf16_t* ffn_w2_t = (bf16_t*)alloc(WDF * 2);
    float*  qkv_bias = (float*)alloc(2304 * 4);
    bf16_t* ln_buf   = (bf16_t*)alloc((size_t)CB * CNQ * CD * 2);
    bf16_t* qkvs     = (bf16_t*)alloc(3 * QSZ * 2);          // q_split | k_split | v_splitT
    bf16_t* kc_split = (bf16_t*)alloc((size_t)CB * CH * CNC * CHD * 2);
    bf16_t* vc_splitT= (bf16_t*)alloc((size_t)CB * CH * CNC * CHD * 2);
    float*  S        = (float*)alloc((size_t)CB * CH * CNQ * CNC * 4);
    bf16_t* bias2d   = (bf16_t*)alloc((size_t)CB * CH * CNQ * CNC * 2);
    bf16_t* attn_m   = (bf16_t*)alloc((size_t)CB * CNQ * CD * 2);
    float*  xbuf     = (float*)alloc((size_t)CB * CNQ * CD * 4);
    bf16_t* ffn_h    = (bf16_t*)alloc((size_t)CB * CNQ * CFFN * 2);
    bf16_t* q_split  = qkvs;
    bf16_t* k_split  = qkvs + QSZ;
    bf16_t* v_splitT = qkvs + 2 * QSZ;

    const dim3 tb(256);
    const float qk_scale = 0.10206207261596575f;  // 96^-0.5

    // weights -> bf16 transposed (8 square transposes in one launch)
    wtrans8_kernel<<<dim3(CD / 32, CD / 32, 8), tb, 0, stream>>>(
        sa_wq, sa_wk, sa_wv, sa_wo, ca_wq, ca_wk, ca_wv, ca_wo,
        qkv_wt, qkv_wt + WDD, qkv_wt + 2 * WDD, sa_wo_t, ca_wq_t, ca_wk_t, ca_wv_t, ca_wo_t);
    wtrans_kernel<<<dim3(CFFN / 32, CD / 32), tb, 0, stream>>>(ffn_w1, ffn_w1_t, CD, CFFN);
    wtrans_kernel<<<dim3(CD / 32, CFFN / 32), tb, 0, stream>>>(ffn_w2, ffn_w2_t, CFFN, CD);
    biascat_kernel<<<9, tb, 0, stream>>>(sa_bq, sa_bk, sa_bv, qkv_bias);
    // relative coordinate bias
    relbias_kernel<<<(CB * CNQ * CNC) / 256, tb, 0, stream>>>(query_coords, context_coords,
                                                              rb_w1, rb_b1, rb_w2, rb_b2, bias2d);
    // ---- self attention ----
    ln_kernel<<<CB * CNQ, tb, 0, stream>>>(query_state, sn_g, sn_b, ln_buf);
    gemm_nt<4,2,64,5,true,false,false,false><<<dim3(2304 / 64, (CB * CNQ) / 128, 1), tb, 0, stream>>>(
        ln_buf, CD, 0, qkv_wt, CD, 0, qkv_bias, nullptr, 0, 0, nullptr, qkvs, 0, 0, CD, CNQ, 1.0f);
    gemm_nt<4,2,96,0,false,false,false,false><<<dim3(CNQ / 64, CNQ / 128, CB * CH), tb, 0, stream>>>(
        q_split, CHD, (long)CNQ * CHD, k_split, CHD, (long)CNQ * CHD,
        nullptr, nullptr, 0, 0, nullptr, S, CNQ, (long)CNQ * CNQ, CHD, 0, qk_scale);
    softmax_kernel<2><<<CB * CH * CNQ, tb, 0, stream>>>(S, CNQ);
    gemm_nt<1,3,64,4,false,false,false,false><<<dim3(1, CNQ / 32, CB * CH), tb, 0, stream>>>(
        (const bf16_t*)S, 2 * CNQ, (long)CNQ * 2 * CNQ, v_splitT, CNQ, (long)CHD * CNQ,
        nullptr, nullptr, 0, 0, nullptr, attn_m, 0, 0, CNQ, CNQ, 1.0f);
    gemm_nt<2,2,64,0,true,false,false,true><<<dim3(CD / 64, (CB * CNQ) / 64, 1), tb, 0, stream>>>(
        attn_m, CD, 0, sa_wo_t, CD, 0, sa_bo, nullptr, 0, 0, query_state, xbuf, CD, 0, CD, 0, 1.0f);
    // ---- cross attention ----
    ln_kernel<<<CB * CNQ, tb, 0, stream>>>(xbuf, cn_g, cn_b, ln_buf);
    gemm_nt<2,2,64,2,true,false,false,false><<<dim3(CD / 64, (CB * CNQ) / 64, 1), tb, 0, stream>>>(
        ln_buf, CD, 0, ca_wq_t, CD, 0, ca_bq, nullptr, 0, 0, nullptr, q_split, 0, 0, CD, CNQ, 1.0f);
    gemm_nt<4,2,64,2,true,false,false,false,true><<<dim3(CD / 64, (CB * CNC) / 128, 1), tb, 0, stream>>>(
        context_k, CD, 0, ca_wk_t, CD, 0, ca_bk, nullptr, 0, 0, nullptr, kc_split, 0, 0, CD, CNC, 1.0f);
    gemm_nt<4,2,64,3,true,false,false,false,true><<<dim3(CD / 64, (CB * CNC) / 128, 1), tb, 0, stream>>>(
        context_v, CD, 0, ca_wv_t, CD, 0, ca_bv, nullptr, 0, 0, nullptr, vc_splitT, 0, 0, CD, CNC, 1.0f);
    gemm_nt<4,2,96,0,false,true,false,false><<<dim3(CNC / 64, CNQ / 128, CB * CH), tb, 0, stream>>>(
        q_split, CHD, (long)CNQ * CHD, kc_split, CHD, (long)CNC * CHD,
        nullptr, bias2d, (long)CNQ * CNC, CNC, nullptr, S, CNC, (long)CNQ * CNC, CHD, 0, qk_scale);
    softmax_kernel<8><<<CB * CH * CNQ, tb, 0, stream>>>(S, CNC);
    gemm_nt<1,3,64,4,false,false,false,false><<<dim3(1, CNQ / 32, CB * CH), tb, 0, stream>>>(
        (const bf16_t*)S, 2 * CNC, (long)CNQ * 2 * CNC, vc_splitT, CNC, (long)CHD * CNC,
        nullptr, nullptr, 0, 0, nullptr, attn_m, 0, 0, CNC, CNQ, 1.0f);
    gemm_nt<2,2,64,0,true,false,false,true><<<dim3(CD / 64, (CB * CNQ) / 64, 1), tb, 0, stream>>>(
        attn_m, CD, 0, ca_wo_t, CD, 0, ca_bo, nullptr, 0, 0, xbuf, xbuf, CD, 0, CD, 0, 1.0f);
    // ---- FFN ----
    ln_kernel<<<CB * CNQ, tb, 0, stream>>>(xbuf, fn_g, fn_b, ln_buf);
    gemm_nt<4,2,64,1,true,false,true,false><<<dim3(CFFN / 64, (CB * CNQ) / 128, 1), tb, 0, stream>>>(
        ln_buf, CD, 0, ffn_w1_t, CD, 0, ffn_b1, nullptr, 0, 0, nullptr, ffn_h, CFFN, 0, CD, 0, 1.0f);
    gemm_nt<2,2,64,0,true,false,false,true><<<dim3(CD / 64, (CB * CNQ) / 64, 1), tb, 0, stream>>>(
        ffn_h, CFFN, 0, ffn_w2_t, CFFN, 0, ffn_b2, nullptr, 0, 0, xbuf, out, CD, 0, CFFN, 0, 1.0f);
}

// Round 9
// 452.821 us; speedup vs baseline: 1.2080x; 1.0729x over previous
//
#include <hip/hip_runtime.h>
#include <hip/hip_bf16.h>

typedef __bf16 bf16x8 __attribute__((ext_vector_type(8)));
typedef float  f32x4  __attribute__((ext_vector_type(4)));
typedef float  f32x2  __attribute__((ext_vector_type(2)));
typedef __hip_bfloat16 bf16_t;

constexpr int CB  = 2;
constexpr int CNQ = 512;
constexpr int CNC = 2048;
constexpr int CD  = 768;
constexpr int CH  = 8;
constexpr int CHD = 96;
constexpr int CFFN = 3072;

// fast gelu: x * sigmoid(1.5957692(x + 0.044715 x^3)); max abs err vs exact ~3e-4
static __device__ __forceinline__ float gelu_f(float x) {
    float x2 = x * x;
    float zn = x * fmaf(x2, -0.07135481f, -1.5957692f);
    float e  = __expf(zn);
    return x * __builtin_amdgcn_rcpf(1.0f + e);
}

// ---------------- LayerNorm: f32 in -> bf16 out, one block per row (D=768) ----------------
__global__ __launch_bounds__(256) void ln_kernel(const float* __restrict__ x,
                                                 const float* __restrict__ g,
                                                 const float* __restrict__ b,
                                                 bf16_t* __restrict__ out) {
    __shared__ float red[8];
    long row = blockIdx.x;
    const float* xr = x + row * CD;
    int t = threadIdx.x;
    float v0 = xr[t], v1 = xr[t + 256], v2 = xr[t + 512];
    float s  = v0 + v1 + v2;
    float sq = v0 * v0 + v1 * v1 + v2 * v2;
    #pragma unroll
    for (int o = 32; o; o >>= 1) { s += __shfl_xor(s, o); sq += __shfl_xor(sq, o); }
    if ((t & 63) == 0) { red[t >> 6] = s; red[4 + (t >> 6)] = sq; }
    __syncthreads();
    s  = red[0] + red[1] + red[2] + red[3];
    sq = red[4] + red[5] + red[6] + red[7];
    float mean = s * (1.0f / 768.0f);
    float var  = sq * (1.0f / 768.0f) - mean * mean;
    float inv  = rsqrtf(var + 1e-5f);
    bf16_t* orow = out + row * CD;
    orow[t]       = __float2bfloat16((v0 - mean) * inv * g[t]       + b[t]);
    orow[t + 256] = __float2bfloat16((v1 - mean) * inv * g[t + 256] + b[t + 256]);
    orow[t + 512] = __float2bfloat16((v2 - mean) * inv * g[t + 512] + b[t + 512]);
}

// ---------------- batched 8x weight transpose 768x768 f32 -> bf16 T ----------------
__global__ __launch_bounds__(256) void wtrans8_kernel(
        const float* W0, const float* W1, const float* W2, const float* W3,
        const float* W4, const float* W5, const float* W6, const float* W7,
        bf16_t* T0, bf16_t* T1, bf16_t* T2, bf16_t* T3,
        bf16_t* T4, bf16_t* T5, bf16_t* T6, bf16_t* T7) {
    const float* Ws[8] = {W0, W1, W2, W3, W4, W5, W6, W7};
    bf16_t*      Ts[8] = {T0, T1, T2, T3, T4, T5, T6, T7};
    const float* W = Ws[blockIdx.z];
    bf16_t*      T = Ts[blockIdx.z];
    __shared__ float tile[32][33];
    int tx = threadIdx.x & 31, ty = threadIdx.x >> 5;
    int bx = blockIdx.x, by = blockIdx.y;
    #pragma unroll
    for (int i = 0; i < 4; ++i)
        tile[ty + i * 8][tx] = W[(long)(by * 32 + ty + i * 8) * CD + bx * 32 + tx];
    __syncthreads();
    #pragma unroll
    for (int i = 0; i < 4; ++i)
        T[(long)(bx * 32 + ty + i * 8) * CD + by * 32 + tx] = __float2bfloat16(tile[tx][ty + i * 8]);
}

// ---------------- generic weight transpose: W (K x N) f32 -> Wt (N x K) bf16 ----------------
__global__ __launch_bounds__(256) void wtrans_kernel(const float* __restrict__ W,
                                                     bf16_t* __restrict__ Wt, int K, int N) {
    __shared__ float tile[32][33];
    int tx = threadIdx.x & 31, ty = threadIdx.x >> 5;
    int bx = blockIdx.x, by = blockIdx.y;
    #pragma unroll
    for (int i = 0; i < 4; ++i) {
        int k = by * 32 + ty + i * 8;
        tile[ty + i * 8][tx] = W[(long)k * N + bx * 32 + tx];
    }
    __syncthreads();
    #pragma unroll
    for (int i = 0; i < 4; ++i) {
        int n = bx * 32 + ty + i * 8;
        Wt[(long)n * K + by * 32 + tx] = __float2bfloat16(tile[tx][ty + i * 8]);
    }
}

// ---------------- concat 3 x 768 f32 biases -> 2304 ----------------
__global__ __launch_bounds__(256) void biascat_kernel(const float* __restrict__ b0,
                                                      const float* __restrict__ b1,
                                                      const float* __restrict__ b2,
                                                      float* __restrict__ out) {
    int i = blockIdx.x * 256 + threadIdx.x;   // 0..2303
    float v = i < 768 ? b0[i] : (i < 1536 ? b1[i - 768] : b2[i - 1536]);
    out[i] = v;
}

// ---------------- relative coordinate bias via MFMA projection -> (B,H,NQ,NC) bf16 ----------------
// Each wave handles 16 consecutive pairs (same q, 16 consecutive k). Lane computes the
// hidden gelu values for A-fragment slots (row=l&15 -> pair, k=(l>>4)*8+e -> hidden j),
// then 2 chained mfma_16x16x32 project 64->8 (w2 cols 8..15 zero). C: col=l&15=h,
// row=(l>>4)*4+r -> 4 consecutive k -> one 8B store per lane (lanes with h>=8 idle).
__global__ __launch_bounds__(256) void relbias_mfma_kernel(
        const float* __restrict__ qc, const float* __restrict__ cc,
        const float* __restrict__ w1, const float* __restrict__ b1,
        const float* __restrict__ w2, const float* __restrict__ b2,
        bf16_t* __restrict__ bias) {
    const int tid  = threadIdx.x;
    const int wave = tid >> 6, lane = tid & 63;
    const int row  = lane & 15, grp = lane >> 4;
    const int g8   = grp * 8;
    // per-lane hidden-layer weights: s=0 -> j=g8+e, s=1 -> j=32+g8+e
    float a0[8], a1[8], bb0[8], bb1[8], c0[8], c1[8];
    #pragma unroll
    for (int e = 0; e < 8; ++e) {
        a0[e]  = w1[g8 + e];       a1[e]  = w1[32 + g8 + e];
        bb0[e] = w1[64 + g8 + e];  bb1[e] = w1[96 + g8 + e];
        c0[e]  = b1[g8 + e];       c1[e]  = b1[32 + g8 + e];
    }
    const int hcol = row;                       // this lane's output column
    bf16x8 bs0 = {}, bs1 = {};
    if (hcol < CH) {
        #pragma unroll
        for (int e = 0; e < 8; ++e) {
            bs0[e] = (__bf16)w2[(g8 + e) * CH + hcol];
            bs1[e] = (__bf16)w2[(32 + g8 + e) * CH + hcol];
        }
    }
    const float b2h = (hcol < CH) ? b2[hcol] : 0.0f;
    const long NT = (long)CB * CNQ * CNC / 64;  // 64 pairs per block (4 waves x 16)
    for (long t = blockIdx.x; t < NT; t += gridDim.x) {
        long pbase = t * 64 + wave * 16;
        long p = pbase + row;
        int k = (int)(p & (CNC - 1));
        int q = (int)((p >> 11) & (CNQ - 1));
        int b = (int)(p >> 20);
        float d0 = qc[((long)b * CNQ + q) * 2]     - cc[((long)b * CNC + k) * 2];
        float d1 = qc[((long)b * CNQ + q) * 2 + 1] - cc[((long)b * CNC + k) * 2 + 1];
        bf16x8 af0, af1;
        #pragma unroll
        for (int e = 0; e < 8; ++e) {
            float x = fmaf(d0, a0[e], fmaf(d1, bb0[e], c0[e]));
            float x2 = x * x;
            float zn = x * fmaf(x2, -0.07135481f, -1.5957692f);
            af0[e] = (__bf16)(x * __builtin_amdgcn_rcpf(1.0f + __expf(zn)));
            x  = fmaf(d0, a1[e], fmaf(d1, bb1[e], c1[e]));
            x2 = x * x;
            zn = x * fmaf(x2, -0.07135481f, -1.5957692f);
            af1[e] = (__bf16)(x * __builtin_amdgcn_rcpf(1.0f + __expf(zn)));
        }
        f32x4 acc = {};
        acc = __builtin_amdgcn_mfma_f32_16x16x32_bf16(af0, bs0, acc, 0, 0, 0);
        acc = __builtin_amdgcn_mfma_f32_16x16x32_bf16(af1, bs1, acc, 0, 0, 0);
        if (hcol < CH) {
            long pr = pbase + grp * 4;          // first of this lane's 4 pair-rows
            int kk = (int)(pr & (CNC - 1));
            int qq = (int)((pr >> 11) & (CNQ - 1));
            int bb = (int)(pr >> 20);
            union { ushort4 u; bf16_t h[4]; } pk;
            pk.h[0] = __float2bfloat16(acc[0] + b2h);
            pk.h[1] = __float2bfloat16(acc[1] + b2h);
            pk.h[2] = __float2bfloat16(acc[2] + b2h);
            pk.h[3] = __float2bfloat16(acc[3] + b2h);
            *(ushort4*)&bias[((long)(bb * CH + hcol) * CNQ + qq) * CNC + kk] = pk.u;
        }
    }
}

// ---------------- row softmax in place: f32 row -> bf16 row ----------------
template<int NPT>
__global__ __launch_bounds__(256) void softmax_kernel(float* __restrict__ S, long ld) {
    __shared__ float red[8];
    long row = blockIdx.x;
    float* base = S + row * ld;
    int t = threadIdx.x;
    const int c0 = t * NPT;
    float v[NPT];
    #pragma unroll
    for (int i = 0; i < NPT; ++i) v[i] = base[c0 + i];
    float m = v[0];
    #pragma unroll
    for (int i = 1; i < NPT; ++i) m = fmaxf(m, v[i]);
    #pragma unroll
    for (int o = 32; o; o >>= 1) m = fmaxf(m, __shfl_xor(m, o));
    if ((t & 63) == 0) red[t >> 6] = m;
    __syncthreads();
    m = fmaxf(fmaxf(red[0], red[1]), fmaxf(red[2], red[3]));
    float s = 0.0f;
    #pragma unroll
    for (int i = 0; i < NPT; ++i) { v[i] = __expf(v[i] - m); s += v[i]; }
    #pragma unroll
    for (int o = 32; o; o >>= 1) s += __shfl_xor(s, o);
    __syncthreads();
    if ((t & 63) == 0) red[4 + (t >> 6)] = s;
    __syncthreads();
    s = red[4] + red[5] + red[6] + red[7];
    float inv = 1.0f / s;
    bf16_t* ob = (bf16_t*)base;
    #pragma unroll
    for (int i = 0; i < NPT; ++i) ob[c0 + i] = __float2bfloat16(v[i] * inv);
}

// ---------------- generic NT MFMA GEMM ----------------
// OUT: 0 f32 plain, 1 bf16 plain, 2 bf16 head-split (B,H,NR,HD), 3 bf16 head-split-T (B,H,HD,NR),
//      4 bf16 merge96 (z=(b,h)), 5 fused-QKV split writer, 6 merged K/V projection
//      (z=0: A/Bt/bias -> head-split into Cout; z=1: A2/Bt2/biasB -> head-split-T into Cout2).
// AF32: A is f32, converted to bf16 during LDS staging.
template<int MF, int NF, int BK, int OUT, bool BIAS, bool B2D, bool GELU_E, bool RES, bool AF32 = false>
__global__ __launch_bounds__(256) void gemm_nt(
        const void* __restrict__ Araw, long ldA, long zsA,
        const bf16_t* __restrict__ Bt, long ldB, long zsB,
        const float* __restrict__ bias,
        const bf16_t* __restrict__ b2d, long zs2d, long ld2d,
        const float* __restrict__ res,
        void* __restrict__ Cout, long ldC, long zsC,
        int K, int NR, float scale,
        const void* __restrict__ Araw2, const bf16_t* __restrict__ Bt2,
        const float* __restrict__ biasB, void* __restrict__ Cout2) {
    constexpr int BM = MF * 32, BN = NF * 32;
    constexpr int PAD = 4, LDT = BK + PAD;   // stride mod 32 = 4 words: conflict-free b128 r/w
    constexpr int SEGS = BK / 8;
    static_assert((BN * SEGS) % 256 == 0, "B staging divisibility");
    __shared__ __bf16 As[BM * LDT];
    __shared__ __bf16 Bs[BN * LDT];
    const int tid = threadIdx.x;
    const int z = blockIdx.z;
    const int m0 = blockIdx.y * BM, n0 = blockIdx.x * BN;
    const bf16_t* Ab = nullptr; const float* Af = nullptr;
    if constexpr (AF32) Af = (const float*)Araw + (long)z * zsA + (long)m0 * ldA;
    else                Ab = (const bf16_t*)Araw + (long)z * zsA + (long)m0 * ldA;
    const bf16_t* Bb = Bt + (long)z * zsB + (long)n0 * ldB;
    const float* biasp = bias;
    if constexpr (OUT == 6) {
        if (z == 1) {
            if constexpr (AF32) Af = (const float*)Araw2 + (long)m0 * ldA;
            else                Ab = (const bf16_t*)Araw2 + (long)m0 * ldA;
            Bb = Bt2 + (long)n0 * ldB;
            biasp = biasB;
        }
    }
    const int w = tid >> 6, lane = tid & 63;
    const int wm = w >> 1, wn = w & 1;
    const int l15 = lane & 15, l4 = lane >> 4;
    f32x4 acc[MF][NF] = {};
    for (int k0 = 0; k0 < K; k0 += BK) {
        if constexpr (AF32) {
            constexpr int SEGA = BK / 4;
            static_assert((BM * SEGA) % 256 == 0, "A f32 staging divisibility");
            #pragma unroll
            for (int it = 0; it < (BM * SEGA) / 256; ++it) {
                int c = tid + it * 256;
                int r = c / SEGA, sg = c % SEGA;
                float4 v = *(const float4*)&Af[(long)r * ldA + k0 + sg * 4];
                union { bf16_t b[4]; uint2 u; } cv;
                cv.b[0] = __float2bfloat16(v.x); cv.b[1] = __float2bfloat16(v.y);
                cv.b[2] = __float2bfloat16(v.z); cv.b[3] = __float2bfloat16(v.w);
                *(uint2*)&As[r * LDT + sg * 4] = cv.u;
            }
        } else {
            static_assert((BM * SEGS) % 256 == 0 || AF32, "A staging divisibility");
            #pragma unroll
            for (int it = 0; it < (BM * SEGS) / 256; ++it) {
                int c = tid + it * 256;
                int r = c / SEGS, sg = c % SEGS;
                *(bf16x8*)&As[r * LDT + sg * 8] = *(const bf16x8*)&Ab[(long)r * ldA + k0 + sg * 8];
            }
        }
        #pragma unroll
        for (int it = 0; it < (BN * SEGS) / 256; ++it) {
            int c = tid + it * 256;
            int r = c / SEGS, sg = c % SEGS;
            *(bf16x8*)&Bs[r * LDT + sg * 8] = *(const bf16x8*)&Bb[(long)r * ldB + k0 + sg * 8];
        }
        __syncthreads();
        #pragma unroll
        for (int s = 0; s < BK / 32; ++s) {
            bf16x8 af[MF], bfr[NF];
            #pragma unroll
            for (int i = 0; i < MF; ++i)
                af[i] = *(const bf16x8*)&As[(wm * MF * 16 + i * 16 + l15) * LDT + s * 32 + l4 * 8];
            #pragma unroll
            for (int j = 0; j < NF; ++j)
                bfr[j] = *(const bf16x8*)&Bs[(wn * NF * 16 + j * 16 + l15) * LDT + s * 32 + l4 * 8];
            #pragma unroll
            for (int i = 0; i < MF; ++i)
                #pragma unroll
                for (int j = 0; j < NF; ++j)
                    acc[i][j] = __builtin_amdgcn_mfma_f32_16x16x32_bf16(af[i], bfr[j], acc[i][j], 0, 0, 0);
        }
        __syncthreads();
    }
    #pragma unroll
    for (int i = 0; i < MF; ++i) {
        const int rbase = m0 + wm * MF * 16 + i * 16 + l4 * 4;
        #pragma unroll
        for (int j = 0; j < NF; ++j) {
            const int col = n0 + wn * NF * 16 + j * 16 + l15;
            #pragma unroll
            for (int r = 0; r < 4; ++r) {
                int row = rbase + r;
                float v = acc[i][j][r] * scale;
                if constexpr (BIAS) v += biasp[col];
                if constexpr (B2D)  v += __bfloat162float(b2d[(long)z * zs2d + (long)row * ld2d + col]);
                if constexpr (GELU_E) v = gelu_f(v);
                if constexpr (RES)  v += res[(long)row * ldC + col];
                if constexpr (OUT == 0) {
                    ((float*)Cout)[(long)z * zsC + (long)row * ldC + col] = v;
                } else if constexpr (OUT == 1) {
                    ((bf16_t*)Cout)[(long)z * zsC + (long)row * ldC + col] = __float2bfloat16(v);
                } else if constexpr (OUT == 2) {
                    int bb = row / NR, n = row - bb * NR;
                    int hh = col / CHD, dd = col - hh * CHD;
                    ((bf16_t*)Cout)[((long)(bb * CH + hh) * NR + n) * CHD + dd] = __float2bfloat16(v);
                } else if constexpr (OUT == 3) {
                    int bb = row / NR, n = row - bb * NR;
                    int hh = col / CHD, dd = col - hh * CHD;
                    ((bf16_t*)Cout)[((long)(bb * CH + hh) * CHD + dd) * NR + n] = __float2bfloat16(v);
                } else if constexpr (OUT == 4) {
                    int bb = z / CH, hh = z - bb * CH;
                    ((bf16_t*)Cout)[((long)bb * CNQ + row) * CD + hh * CHD + col] = __float2bfloat16(v);
                } else if constexpr (OUT == 5) { // fused QKV, col in [0,2304)
                    constexpr long QSZ5 = (long)CB * CH * CNQ * CHD;
                    int part = col / CD;            // 0=q 1=k 2=v
                    int c = col - part * CD;
                    int hh = c / CHD, dd = c - hh * CHD;
                    int bb = row / CNQ, n = row - bb * CNQ;
                    long off;
                    if (part == 0)      off = ((long)(bb * CH + hh) * CNQ + n) * CHD + dd;
                    else if (part == 1) off = QSZ5 + ((long)(bb * CH + hh) * CNQ + n) * CHD + dd;
                    else                off = 2 * QSZ5 + ((long)(bb * CH + hh) * CHD + dd) * CNQ + n;
                    ((bf16_t*)Cout)[off] = __float2bfloat16(v);
                } else { // OUT == 6: merged K/V projection
                    int bb = row / NR, n = row - bb * NR;
                    int hh = col / CHD, dd = col - hh * CHD;
                    if (z == 0)
                        ((bf16_t*)Cout)[((long)(bb * CH + hh) * NR + n) * CHD + dd] = __float2bfloat16(v);
                    else
                        ((bf16_t*)Cout2)[((long)(bb * CH + hh) * CHD + dd) * NR + n] = __float2bfloat16(v);
                }
            }
        }
    }
}

extern "C" void kernel_launch(void* const* d_in, const int* in_sizes, int n_in,
                              void* d_out, int out_size, void* d_ws, size_t ws_size,
                              hipStream_t stream) {
    const float* query_state    = (const float*)d_in[0];
    const float* context_k      = (const float*)d_in[1];
    const float* context_v      = (const float*)d_in[2];
    const float* query_coords   = (const float*)d_in[3];
    const float* context_coords = (const float*)d_in[4];
    const float* sn_g = (const float*)d_in[5];  const float* sn_b = (const float*)d_in[6];
    const float* sa_wq = (const float*)d_in[7];  const float* sa_bq = (const float*)d_in[8];
    const float* sa_wk = (const float*)d_in[9];  const float* sa_bk = (const float*)d_in[10];
    const float* sa_wv = (const float*)d_in[11]; const float* sa_bv = (const float*)d_in[12];
    const float* sa_wo = (const float*)d_in[13]; const float* sa_bo = (const float*)d_in[14];
    const float* cn_g = (const float*)d_in[15];  const float* cn_b = (const float*)d_in[16];
    const float* ca_wq = (const float*)d_in[17]; const float* ca_bq = (const float*)d_in[18];
    const float* ca_wk = (const float*)d_in[19]; const float* ca_bk = (const float*)d_in[20];
    const float* ca_wv = (const float*)d_in[21]; const float* ca_bv = (const float*)d_in[22];
    const float* ca_wo = (const float*)d_in[23]; const float* ca_bo = (const float*)d_in[24];
    const float* rb_w1 = (const float*)d_in[25]; const float* rb_b1 = (const float*)d_in[26];
    const float* rb_w2 = (const float*)d_in[27]; const float* rb_b2 = (const float*)d_in[28];
    const float* fn_g = (const float*)d_in[29];  const float* fn_b = (const float*)d_in[30];
    const float* ffn_w1 = (const float*)d_in[31]; const float* ffn_b1 = (const float*)d_in[32];
    const float* ffn_w2 = (const float*)d_in[33]; const float* ffn_b2 = (const float*)d_in[34];
    float* out = (float*)d_out;

    char* p = (char*)d_ws;
    auto alloc = [&](size_t bytes) -> char* {
        char* r = p; p += (bytes + 255) & ~(size_t)255; return r;
    };
    const size_t WDD = (size_t)CD * CD, WDF = (size_t)CD * CFFN;
    const size_t QSZ = (size_t)CB * CH * CNQ * CHD;
    bf16_t* qkv_wt  = (bf16_t*)alloc(3 * WDD * 2);          // [wq^T | wk^T | wv^T]
    bf16_t* sa_wo_t = (bf16_t*)alloc(WDD * 2);
    bf16_t* ca_wq_t = (bf16_t*)alloc(WDD * 2);
    bf16_t* ca_wk_t = (bf16_t*)alloc(WDD * 2);
    bf16_t* ca_wv_t = (bf16_t*)alloc(WDD * 2);
    bf16_t* ca_wo_t = (bf16_t*)alloc(WDD * 2);
    bf16_t* ffn_w1_t = (bf16_t*)alloc(WDF * 2);
    bf16_t* ffn_w2_t = (bf16_t*)alloc(WDF * 2);
    float*  qkv_bias = (float*)alloc(2304 * 4);
    bf16_t* ln_buf   = (bf16_t*)alloc((size_t)CB * CNQ * CD * 2);
    bf16_t* qkvs     = (bf16_t*)alloc(3 * QSZ * 2);          // q_split | k_split | v_splitT
    bf16_t* kc_split = (bf16_t*)alloc((size_t)CB * CH * CNC * CHD * 2);
    bf16_t* vc_splitT= (bf16_t*)alloc((size_t)CB * CH * CNC * CHD * 2);
    float*  S        = (float*)alloc((size_t)CB * CH * CNQ * CNC * 4);
    bf16_t* bias2d   = (bf16_t*)alloc((size_t)CB * CH * CNQ * CNC * 2);
    bf16_t* attn_m   = (bf16_t*)alloc((size_t)CB * CNQ * CD * 2);
    float*  xbuf     = (float*)alloc((size_t)CB * CNQ * CD * 4);
    bf16_t* ffn_h    = (bf16_t*)alloc((size_t)CB * CNQ * CFFN * 2);
    bf16_t* q_split  = qkvs;
    bf16_t* k_split  = qkvs + QSZ;
    bf16_t* v_splitT = qkvs + 2 * QSZ;

    const dim3 tb(256);
    const float qk_scale = 0.10206207261596575f;  // 96^-0.5
    #define NUL4 nullptr, nullptr, nullptr, nullptr

    // weights -> bf16 transposed (8 square transposes in one launch)
    wtrans8_kernel<<<dim3(CD / 32, CD / 32, 8), tb, 0, stream>>>(
        sa_wq, sa_wk, sa_wv, sa_wo, ca_wq, ca_wk, ca_wv, ca_wo,
        qkv_wt, qkv_wt + WDD, qkv_wt + 2 * WDD, sa_wo_t, ca_wq_t, ca_wk_t, ca_wv_t, ca_wo_t);
    wtrans_kernel<<<dim3(CFFN / 32, CD / 32), tb, 0, stream>>>(ffn_w1, ffn_w1_t, CD, CFFN);
    wtrans_kernel<<<dim3(CD / 32, CFFN / 32), tb, 0, stream>>>(ffn_w2, ffn_w2_t, CFFN, CD);
    biascat_kernel<<<9, tb, 0, stream>>>(sa_bq, sa_bk, sa_bv, qkv_bias);
    // relative coordinate bias (MFMA-projected)
    relbias_mfma_kernel<<<4096, tb, 0, stream>>>(query_coords, context_coords,
                                                 rb_w1, rb_b1, rb_w2, rb_b2, bias2d);
    // ---- self attention ----
    ln_kernel<<<CB * CNQ, tb, 0, stream>>>(query_state, sn_g, sn_b, ln_buf);
    gemm_nt<4,2,64,5,true,false,false,false><<<dim3(2304 / 64, (CB * CNQ) / 128, 1), tb, 0, stream>>>(
        ln_buf, CD, 0, qkv_wt, CD, 0, qkv_bias, nullptr, 0, 0, nullptr, qkvs, 0, 0, CD, CNQ, 1.0f, NUL4);
    gemm_nt<4,2,96,0,false,false,false,false><<<dim3(CNQ / 64, CNQ / 128, CB * CH), tb, 0, stream>>>(
        q_split, CHD, (long)CNQ * CHD, k_split, CHD, (long)CNQ * CHD,
        nullptr, nullptr, 0, 0, nullptr, S, CNQ, (long)CNQ * CNQ, CHD, 0, qk_scale, NUL4);
    softmax_kernel<2><<<CB * CH * CNQ, tb, 0, stream>>>(S, CNQ);
    gemm_nt<1,3,64,4,false,false,false,false><<<dim3(1, CNQ / 32, CB * CH), tb, 0, stream>>>(
        (const bf16_t*)S, 2 * CNQ, (long)CNQ * 2 * CNQ, v_splitT, CNQ, (long)CHD * CNQ,
        nullptr, nullptr, 0, 0, nullptr, attn_m, 0, 0, CNQ, CNQ, 1.0f, NUL4);
    gemm_nt<1,2,64,0,true,false,false,true><<<dim3(CD / 64, (CB * CNQ) / 32, 1), tb, 0, stream>>>(
        attn_m, CD, 0, sa_wo_t, CD, 0, sa_bo, nullptr, 0, 0, query_state, xbuf, CD, 0, CD, 0, 1.0f, NUL4);
    // ---- cross attention ----
    ln_kernel<<<CB * CNQ, tb, 0, stream>>>(xbuf, cn_g, cn_b, ln_buf);
    gemm_nt<1,2,64,2,true,false,false,false><<<dim3(CD / 64, (CB * CNQ) / 32, 1), tb, 0, stream>>>(
        ln_buf, CD, 0, ca_wq_t, CD, 0, ca_bq, nullptr, 0, 0, nullptr, q_split, 0, 0, CD, CNQ, 1.0f, NUL4);
    gemm_nt<4,2,64,6,true,false,false,false,true><<<dim3(CD / 64, (CB * CNC) / 128, 2), tb, 0, stream>>>(
        context_k, CD, 0, ca_wk_t, CD, 0, ca_bk, nullptr, 0, 0, nullptr, kc_split, 0, 0, CD, CNC, 1.0f,
        context_v, ca_wv_t, ca_bv, vc_splitT);
    gemm_nt<4,2,96,0,false,true,false,false><<<dim3(CNC / 64, CNQ / 128, CB * CH), tb, 0, stream>>>(
        q_split, CHD, (long)CNQ * CHD, kc_split, CHD, (long)CNC * CHD,
        nullptr, bias2d, (long)CNQ * CNC, CNC, nullptr, S, CNC, (long)CNQ * CNC, CHD, 0, qk_scale, NUL4);
    softmax_kernel<8><<<CB * CH * CNQ, tb, 0, stream>>>(S, CNC);
    gemm_nt<1,3,64,4,false,false,false,false><<<dim3(1, CNQ / 32, CB * CH), tb, 0, stream>>>(
        (const bf16_t*)S, 2 * CNC, (long)CNQ * 2 * CNC, vc_splitT, CNC, (long)CHD * CNC,
        nullptr, nullptr, 0, 0, nullptr, attn_m, 0, 0, CNC, CNQ, 1.0f, NUL4);
    gemm_nt<1,2,64,0,true,false,false,true><<<dim3(CD / 64, (CB * CNQ) / 32, 1), tb, 0, stream>>>(
        attn_m, CD, 0, ca_wo_t, CD, 0, ca_bo, nullptr, 0, 0, xbuf, xbuf, CD, 0, CD, 0, 1.0f, NUL4);
    // ---- FFN ----
    ln_kernel<<<CB * CNQ, tb, 0, stream>>>(xbuf, fn_g, fn_b, ln_buf);
    gemm_nt<4,2,64,1,true,false,true,false><<<dim3(CFFN / 64, (CB * CNQ) / 128, 1), tb, 0, stream>>>(
        ln_buf, CD, 0, ffn_w1_t, CD, 0, ffn_b1, nullptr, 0, 0, nullptr, ffn_h, CFFN, 0, CD, 0, 1.0f, NUL4);
    gemm_nt<1,2,64,0,true,false,false,true><<<dim3(CD / 64, (CB * CNQ) / 32, 1), tb, 0, stream>>>(
        ffn_h, CFFN, 0, ffn_w2_t, CFFN, 0, ffn_b2, nullptr, 0, 0, xbuf, out, CD, 0, CFFN, 0, 1.0f, NUL4);
    #undef NUL4
}